// Round 14
// baseline (287.604 us; speedup 1.0000x reference)
//
#include <hip/hip_runtime.h>
#include <cstdint>
#include <cstddef>

// ---------------------------------------------------------------------------
// DeductionNetworkSingleLayer.  R14 = R13 with flash_mha staging upgraded to
// the verified T3/T4 minimum: double-buffered K AND V (144KB LDS), 2-tile
// deep prefetch, counted s_waitcnt vmcnt(8) + raw s_barrier (no vmcnt(0)
// drain in the main loop).  Math/layout byte-identical to R13; only the
// sync/staging skeleton changes.  R13 diagnosis: per-tile compute (~160cyc)
// can't cover 1-deep stage latency (~600-900cyc) -> ~50% stall at drains.
// ---------------------------------------------------------------------------

typedef unsigned short u16;
typedef __attribute__((ext_vector_type(8))) short bf16x8;
typedef __attribute__((ext_vector_type(4))) short s16x4;
typedef __attribute__((ext_vector_type(4))) float f32x4;

__device__ __forceinline__ float b2f(u16 u){
  union { unsigned int i; float f; } v; v.i = ((unsigned int)u) << 16; return v.f;
}
__device__ __forceinline__ u16 f2b(float f){
  union { float f; unsigned int i; } v; v.f = f;
  unsigned int u = v.i;
  unsigned int r = (u + 0x7FFFu + ((u >> 16) & 1u)) >> 16;
  return (u16)r;
}
__device__ __forceinline__ f32x4 mfma16(bf16x8 a, bf16x8 b, f32x4 c){
  return __builtin_amdgcn_mfma_f32_16x16x32_bf16(a, b, c, 0, 0, 0);
}
__device__ __forceinline__ void gload_lds16(const void* g, void* l){
  __builtin_amdgcn_global_load_lds(
      (const __attribute__((address_space(1))) unsigned int*)g,
      (__attribute__((address_space(3))) unsigned int*)l, 16, 0, 0);
}

// ---------------------------------------------------------------------------
__global__ void detect_kernel(const u16* __restrict__ q, int* __restrict__ flag){
  __shared__ int cnt;
  if (threadIdx.x == 0) cnt = 0;
  __syncthreads();
  int c = 0;
  for (int i = threadIdx.x; i < 2048; i += 256){
    u16 u = q[i];
    int e = (u >> 7) & 0xFF;
    if (e >= 140) c++;
  }
  atomicAdd(&cnt, c);
  __syncthreads();
  if (threadIdx.x == 0) *flag = (cnt > 64) ? 1 : 0;   // 1 => inputs are fp32
}

// ---------------------------------------------------------------------------
struct ConvJobs {
  const void* src[18];
  void*       dst[18];
  void*       dst2[18];
  int         n[18];
  int         mode[18];   // 0 = bf16 hi, 1 = bf16 hi+lo, 2 = f32 out
};

__global__ void convert_all(ConvJobs J, const int* __restrict__ flag){
  const int j = blockIdx.y;
  const int n = J.n[j];
  const int mode = J.mode[j];
  const int isf = *flag;
  for (int i = blockIdx.x * blockDim.x + threadIdx.x; i < n; i += gridDim.x * blockDim.x){
    if (mode == 2){
      float f = isf ? ((const float*)J.src[j])[i] : b2f(((const u16*)J.src[j])[i]);
      ((float*)J.dst[j])[i] = f;
    } else {
      u16 hi, lo = 0;
      if (isf){
        float f = ((const float*)J.src[j])[i];
        hi = f2b(f);
        if (mode == 1) lo = f2b(f - b2f(hi));
      } else {
        hi = ((const u16*)J.src[j])[i];
      }
      ((u16*)J.dst[j])[i] = hi;
      if (mode == 1) ((u16*)J.dst2[j])[i] = lo;
    }
  }
}

// ---------------------------------------------------------------------------
// GEMM 128x128 (B^T pattern, swizzled LDS) for the QKV projections.
// STORE: 0 = bf16 row-major, 2 = bf16 transposed-per-head
// ---------------------------------------------------------------------------
template<int STORE, bool RELU>
__global__ __launch_bounds__(256) void gemm_bt(
    const u16* __restrict__ X, const u16* __restrict__ W,
    const float* __restrict__ bias, void* __restrict__ outp,
    int M, int N, int K)
{
  __shared__ __align__(16) u16 lx[128 * 64];
  __shared__ __align__(16) u16 lw[128 * 64];
  const int tid = threadIdx.x;
  const int l = tid & 63, w = tid >> 6;
  const int lg = l >> 4, lr = l & 15;
  const int wr = w >> 1, wc = w & 1;
  const int m0 = blockIdx.x * 128;
  const int n0 = blockIdx.y * 128;

  f32x4 acc[4][4];
#pragma unroll
  for (int mi = 0; mi < 4; mi++)
#pragma unroll
    for (int ni = 0; ni < 4; ni++) acc[mi][ni] = (f32x4){0.f, 0.f, 0.f, 0.f};

  const int nkt = K >> 6;
  for (int kt = 0; kt < nkt; ++kt){
    __syncthreads();
#pragma unroll
    for (int it = 0; it < 4; ++it){
      int c = it * 256 + tid;
      int row = c >> 3, j = c & 7;
      int sj = (j ^ (row & 7)) * 8;
      const u16* gx = X + (size_t)(m0 + row) * K + kt * 64 + sj;
      gload_lds16(gx, (char*)lx + c * 16);
      const u16* gw = W + (size_t)(n0 + row) * K + kt * 64 + sj;
      gload_lds16(gw, (char*)lw + c * 16);
    }
    __syncthreads();
#pragma unroll
    for (int ks = 0; ks < 2; ++ks){
      bf16x8 af[4], bfv[4];
      const int swz = ((ks * 4 + lg) ^ (lr & 7)) * 8;
#pragma unroll
      for (int mi = 0; mi < 4; mi++)
        af[mi] = *(const bf16x8*)(lx + (wr * 64 + mi * 16 + lr) * 64 + swz);
#pragma unroll
      for (int ni = 0; ni < 4; ni++)
        bfv[ni] = *(const bf16x8*)(lw + (wc * 64 + ni * 16 + lr) * 64 + swz);
#pragma unroll
      for (int mi = 0; mi < 4; mi++)
#pragma unroll
        for (int ni = 0; ni < 4; ni++)
          acc[mi][ni] = mfma16(af[mi], bfv[ni], acc[mi][ni]);
    }
  }

#pragma unroll
  for (int mi = 0; mi < 4; mi++)
#pragma unroll
    for (int ni = 0; ni < 4; ni++){
      const int gr0 = m0 + wr * 64 + mi * 16 + lg * 4;
      const int gc  = n0 + wc * 64 + ni * 16 + lr;
      const float bv = bias ? bias[gc] : 0.f;
      if (STORE == 2){
        const int b = gr0 >> 11, sk0 = gr0 & 2047;
        const int h = gc >> 8,  d   = gc & 255;
        s16x4 pk;
#pragma unroll
        for (int r = 0; r < 4; r++){
          float v = acc[mi][ni][r] + bv;
          pk[r] = (short)f2b(v);
        }
        *(s16x4*)((u16*)outp + ((size_t)((b << 3) + h) * 256 + d) * 2048 + sk0) = pk;
      } else {
#pragma unroll
        for (int r = 0; r < 4; r++){
          float v = acc[mi][ni][r] + bv;
          if (RELU) v = fmaxf(v, 0.f);
          size_t idx = (size_t)(gr0 + r) * N + gc;
          if (STORE == 0) ((u16*)outp)[idx] = f2b(v);
          else            ((float*)outp)[idx] = v;
        }
      }
    }
}

// ---------------------------------------------------------------------------
// GEMM 64x64 tile variant: fills the grid for small-N GEMMs (wo, w1, w2).
// ---------------------------------------------------------------------------
template<int STORE, bool RELU>
__global__ __launch_bounds__(256) void gemm_bt64(
    const u16* __restrict__ X, const u16* __restrict__ W,
    const float* __restrict__ bias, void* __restrict__ outp,
    int M, int N, int K)
{
  __shared__ __align__(16) u16 lx[64 * 64];
  __shared__ __align__(16) u16 lw[64 * 64];
  const int tid = threadIdx.x;
  const int l = tid & 63, w = tid >> 6;
  const int lg = l >> 4, lr = l & 15;
  const int wr = w >> 1, wc = w & 1;
  const int m0 = blockIdx.x * 64;
  const int n0 = blockIdx.y * 64;

  f32x4 acc[2][2];
#pragma unroll
  for (int mi = 0; mi < 2; mi++)
#pragma unroll
    for (int ni = 0; ni < 2; ni++) acc[mi][ni] = (f32x4){0.f, 0.f, 0.f, 0.f};

  const int nkt = K >> 6;
  for (int kt = 0; kt < nkt; ++kt){
    __syncthreads();
#pragma unroll
    for (int it = 0; it < 2; ++it){
      int c = it * 256 + tid;
      int row = c >> 3, j = c & 7;
      int sj = (j ^ (row & 7)) * 8;
      const u16* gx = X + (size_t)(m0 + row) * K + kt * 64 + sj;
      gload_lds16(gx, (char*)lx + c * 16);
      const u16* gw = W + (size_t)(n0 + row) * K + kt * 64 + sj;
      gload_lds16(gw, (char*)lw + c * 16);
    }
    __syncthreads();
#pragma unroll
    for (int ks = 0; ks < 2; ++ks){
      bf16x8 af[2], bfv[2];
      const int swz = ((ks * 4 + lg) ^ (lr & 7)) * 8;
#pragma unroll
      for (int mi = 0; mi < 2; mi++)
        af[mi] = *(const bf16x8*)(lx + (wr * 32 + mi * 16 + lr) * 64 + swz);
#pragma unroll
      for (int ni = 0; ni < 2; ni++)
        bfv[ni] = *(const bf16x8*)(lw + (wc * 32 + ni * 16 + lr) * 64 + swz);
#pragma unroll
      for (int mi = 0; mi < 2; mi++)
#pragma unroll
        for (int ni = 0; ni < 2; ni++)
          acc[mi][ni] = mfma16(af[mi], bfv[ni], acc[mi][ni]);
    }
  }

#pragma unroll
  for (int mi = 0; mi < 2; mi++)
#pragma unroll
    for (int ni = 0; ni < 2; ni++){
      const int gr0 = m0 + wr * 32 + mi * 16 + lg * 4;
      const int gc  = n0 + wc * 32 + ni * 16 + lr;
      const float bv = bias ? bias[gc] : 0.f;
#pragma unroll
      for (int r = 0; r < 4; r++){
        float v = acc[mi][ni][r] + bv;
        if (RELU) v = fmaxf(v, 0.f);
        size_t idx = (size_t)(gr0 + r) * N + gc;
        if (STORE == 0) ((u16*)outp)[idx] = f2b(v);
        else            ((float*)outp)[idx] = v;
      }
    }
}

// ---------------------------------------------------------------------------
// 64x64 bf16 transpose: At[b][d][sk] = Ac[b][sk][d]
// ---------------------------------------------------------------------------
__global__ __launch_bounds__(256) void transpose_k(const u16* __restrict__ src, u16* __restrict__ dst){
  __shared__ u16 t[64][72];
  const int b   = blockIdx.z;
  const int sk0 = blockIdx.x * 64;
  const int d0  = blockIdx.y * 64;
  const int tid = threadIdx.x;
  union U8 { bf16x8 v; u16 e[8]; };
#pragma unroll
  for (int half = 0; half < 2; ++half){
    int c = half * 256 + tid;
    int r = c >> 3, c8 = (c & 7) * 8;
    U8 u; u.v = *(const bf16x8*)(src + ((size_t)b * 2048 + sk0 + r) * 256 + d0 + c8);
#pragma unroll
    for (int i = 0; i < 8; i++) t[r][c8 + i] = u.e[i];
  }
  __syncthreads();
#pragma unroll
  for (int half = 0; half < 2; ++half){
    int c = half * 256 + tid;
    int dr = c >> 3, s8 = (c & 7) * 8;
    U8 u;
#pragma unroll
    for (int i = 0; i < 8; i++) u.e[i] = t[s8 + i][dr];
    *(bf16x8*)(dst + ((size_t)b * 256 + d0 + dr) * 2048 + sk0 + s8) = u.v;
  }
}

// ---------------------------------------------------------------------------
// flash_mha: 512 threads (8 waves), wave owns 16 q-rows.  Double-buffered
// K AND V (144KB LDS), 2-tile-deep prefetch, counted vmcnt(8) + raw
// s_barrier (loads stay in flight across barriers; no vmcnt(0) drain in the
// main loop).  1D grid of 256 with XCD-aware decode (xcd=bid&7 owns 2 heads).
// Per tile: wait vmcnt(8) [K(t),V(t) landed; t+1's 8 loads in flight] ->
// s_barrier -> QK -> softmax -> P -> PV -> s_barrier -> issue K,V(t+2).
// ---------------------------------------------------------------------------
__global__ __launch_bounds__(512, 2) void flash_mha(
    const u16* __restrict__ Qp, const u16* __restrict__ Kp,
    const u16* __restrict__ Vt, u16* __restrict__ outp)
{
  __shared__ __align__(16) u16 bufK[2][64 * 256];   // [64 k][256 e] x2  64KB
  __shared__ __align__(16) u16 bufV[2][256 * 64];   // [256 d][64 k] x2  64KB
  __shared__ __align__(16) u16 ldsP[8][16 * 64];    // per-wave P (swz)  16KB
  const int tid = threadIdx.x, l = tid & 63, w = tid >> 6;   // w in [0,8)
  const int lg = l >> 4, lr = l & 15;
  const int lr7 = lr & 7;
  // XCD-aware decode: bid%8 -> XCD; each XCD owns 2 heads
  const int bid = blockIdx.x;
  const int xcd = bid & 7;
  const int slot = bid >> 3;                 // 0..31
  const int by = xcd * 2 + (slot >> 4);
  const int qt = slot & 15;
  const size_t qkbase = ((size_t)(by >> 3) * 2048) * 2048 + (size_t)(by & 7) * 256;
  const size_t vbase  = (size_t)by * (256 * 2048);
  const int q0 = qt * 128 + w * 16;

  bf16x8 qf[8];
#pragma unroll
  for (int ks = 0; ks < 8; ks++)
    qf[ks] = *(const bf16x8*)(Qp + qkbase +
        (size_t)(q0 + lr) * 2048 + ks * 32 + lg * 8);

  float mrun[4], lpart[4];
#pragma unroll
  for (int r = 0; r < 4; r++){ mrun[r] = -3e38f; lpart[r] = 0.f; }
  f32x4 accO[16];
#pragma unroll
  for (int db = 0; db < 16; db++) accO[db] = (f32x4){0.f, 0.f, 0.f, 0.f};

  // each stage = 4 global_load_lds per thread (vmcnt units)
  auto stageK = [&](int kv0, u16* dst){
#pragma unroll
    for (int it = 0; it < 4; ++it){
      int c = it * 512 + tid;               // 2048 chunks
      int row = c >> 5, j = c & 31;
      const u16* g = Kp + qkbase + (size_t)(kv0 + row) * 2048 + (j ^ (row & 7)) * 8;
      gload_lds16(g, (char*)dst + c * 16);
    }
  };
  auto stageV = [&](int kv0, u16* dst){
#pragma unroll
    for (int it = 0; it < 4; ++it){
      int c = it * 512 + tid;               // 2048 chunks
      int row = c >> 3, j = c & 7;
      const u16* g = Vt + vbase + (size_t)row * 2048 + kv0 + (j ^ (row & 7)) * 8;
      gload_lds16(g, (char*)dst + c * 16);
    }
  };

  // prologue: tiles 0 and 1 in flight (16 loads outstanding per thread)
  stageK(0,  bufK[0]); stageV(0,  bufV[0]);
  stageK(64, bufK[1]); stageV(64, bufV[1]);

  for (int t = 0; t < 32; ++t){
    const int kv0 = t * 64;
    const int cur = t & 1;
    // K(t),V(t) landed when <=8 outstanding (the 8 younger = tile t+1).
    if (t < 31) asm volatile("s_waitcnt vmcnt(8)" ::: "memory");
    else        asm volatile("s_waitcnt vmcnt(0)" ::: "memory");
    asm volatile("s_barrier" ::: "memory");   // all waves' portions landed

    f32x4 s[4];
#pragma unroll
    for (int kb = 0; kb < 4; kb++) s[kb] = (f32x4){0.f, 0.f, 0.f, 0.f};

    __builtin_amdgcn_s_setprio(1);
#pragma unroll
    for (int ks = 0; ks < 8; ks++){
      bf16x8 bfr[4];
      const int swz = (((ks * 4 + lg) ^ lr7)) * 8;
#pragma unroll
      for (int kb = 0; kb < 4; kb++)
        bfr[kb] = *(const bf16x8*)(bufK[cur] + (kb * 16 + lr) * 256 + swz);
#pragma unroll
      for (int kb = 0; kb < 4; kb++)
        s[kb] = mfma16(qf[ks], bfr[kb], s[kb]);
    }
    __builtin_amdgcn_s_setprio(0);

    // ---- online softmax with defer-max (rows q0 + lg*4 + r) ----
    float pm[4];
#pragma unroll
    for (int kb = 0; kb < 4; kb++)
#pragma unroll
      for (int r = 0; r < 4; r++) s[kb][r] *= 0.0625f;
#pragma unroll
    for (int r = 0; r < 4; r++)
      pm[r] = fmaxf(fmaxf(s[0][r], s[1][r]), fmaxf(s[2][r], s[3][r]));
#pragma unroll
    for (int m = 1; m < 16; m <<= 1)
#pragma unroll
      for (int r = 0; r < 4; r++) pm[r] = fmaxf(pm[r], __shfl_xor(pm[r], m));

    float gmax = fmaxf(fmaxf(pm[0] - mrun[0], pm[1] - mrun[1]),
                       fmaxf(pm[2] - mrun[2], pm[3] - mrun[3]));
    if (__any(gmax > 8.0f)){
#pragma unroll
      for (int r = 0; r < 4; r++){
        float mn = fmaxf(mrun[r], pm[r]);
        float corr = __expf(mrun[r] - mn);
        mrun[r] = mn;
        lpart[r] *= corr;
#pragma unroll
        for (int db = 0; db < 16; db++) accO[db][r] *= corr;
      }
    }
    // P store: row = lg*4+r, col = kb*16+lr; chunk-XOR swizzled stride 64
#pragma unroll
    for (int kb = 0; kb < 4; kb++)
#pragma unroll
      for (int r = 0; r < 4; r++){
        float p = __expf(s[kb][r] - mrun[r]);
        lpart[r] += p;
        const int row = lg * 4 + r;
        ldsP[w][(row << 6) + (((kb * 2 + (lr >> 3)) ^ (row & 7)) << 3) + (lr & 7)] = f2b(p);
      }

    // ---- PV (same-wave ldsP dependency; backend inserts lgkmcnt) ----
    __builtin_amdgcn_s_setprio(1);
#pragma unroll
    for (int ks2 = 0; ks2 < 2; ++ks2){
      bf16x8 pa = *(const bf16x8*)(ldsP[w] + (lr << 6) + (((ks2 * 4 + lg) ^ lr7) << 3));
      const int swz = (((ks2 * 4 + lg) ^ lr7)) * 8;
#pragma unroll
      for (int db = 0; db < 16; ++db){
        bf16x8 vb = *(const bf16x8*)(bufV[cur] + (db * 16 + lr) * 64 + swz);
        accO[db] = mfma16(pa, vb, accO[db]);
      }
    }
    __builtin_amdgcn_s_setprio(0);

    asm volatile("s_barrier" ::: "memory");   // all waves done reading buf[cur]
    if (t + 2 < 32){
      stageK(kv0 + 128, bufK[cur]);           // tile t+2 overwrites buf[cur]
      stageV(kv0 + 128, bufV[cur]);
    }
  }

  // epilogue
  float lrun[4];
#pragma unroll
  for (int r = 0; r < 4; r++) lrun[r] = lpart[r];
#pragma unroll
  for (int m = 1; m < 16; m <<= 1)
#pragma unroll
    for (int r = 0; r < 4; r++) lrun[r] += __shfl_xor(lrun[r], m);
  float inv[4];
#pragma unroll
  for (int r = 0; r < 4; r++) inv[r] = 1.f / lrun[r];
#pragma unroll
  for (int db = 0; db < 16; db++)
#pragma unroll
    for (int r = 0; r < 4; r++){
      float v = accO[db][r] * inv[r];
      int q = q0 + lg * 4 + r;
      int d = db * 16 + lr;
      outp[((size_t)(by >> 3) * 2048 + q) * 2048 + (size_t)(by & 7) * 256 + d] = f2b(v);
    }
}

// ---------------------------------------------------------------------------
// flash_b2: split-K branch2, grid (32,2,8).
// ---------------------------------------------------------------------------
__global__ __launch_bounds__(256) void flash_b2(
    const u16* __restrict__ Qh, const u16* __restrict__ Ql,
    const u16* __restrict__ Kh, const u16* __restrict__ Kl,
    const u16* __restrict__ Vt,
    float* __restrict__ Opart, float* __restrict__ mlp,
    const float* __restrict__ p_scale, const int* __restrict__ flagp)
{
  __shared__ __align__(16) u16 bufK[64 * 256];
  __shared__ __align__(16) u16 bufV[256 * 64];
  __shared__ __align__(16) u16 ldsP[4][16 * 72];
  const int tid = threadIdx.x, l = tid & 63, w = tid >> 6;
  const int lg = l >> 4, lr = l & 15;
  const int lr7 = lr & 7;
  const int by = blockIdx.y, qt = blockIdx.x, kc = blockIdx.z;
  const size_t qkbase = (size_t)by * (2048 * 256);
  const size_t vbase  = (size_t)by * (256 * 2048);
  const float scale = *p_scale;
  const int split = *flagp;
  const int kvbase = kc * 256;
  const int q0 = qt * 64 + w * 16;

  bf16x8 qf[8], qfl[8];
#pragma unroll
  for (int ks = 0; ks < 8; ks++)
    qf[ks] = *(const bf16x8*)(Qh + qkbase + (size_t)(q0 + lr) * 256 + ks * 32 + lg * 8);
  if (split){
#pragma unroll
    for (int ks = 0; ks < 8; ks++)
      qfl[ks] = *(const bf16x8*)(Ql + qkbase + (size_t)(q0 + lr) * 256 + ks * 32 + lg * 8);
  } else {
#pragma unroll
    for (int ks = 0; ks < 8; ks++) qfl[ks] = qf[ks];
  }

  float mrun[4], lpart[4];
#pragma unroll
  for (int r = 0; r < 4; r++){ mrun[r] = -3e38f; lpart[r] = 0.f; }
  f32x4 accO[16];
#pragma unroll
  for (int db = 0; db < 16; db++) accO[db] = (f32x4){0.f, 0.f, 0.f, 0.f};

  auto stageK = [&](const u16* __restrict__ src, int kv0){
#pragma unroll
    for (int it = 0; it < 8; ++it){
      int c = it * 256 + tid;
      int row = c >> 5, j = c & 31;
      const u16* g = src + qkbase + (size_t)(kv0 + row) * 256 + (j ^ (row & 7)) * 8;
      gload_lds16(g, (char*)bufK + c * 16);
    }
  };
  auto stageV = [&](int kv0){
#pragma unroll
    for (int it = 0; it < 8; ++it){
      int c = it * 256 + tid;
      int row = c >> 3, j = c & 7;
      const u16* g = Vt + vbase + (size_t)row * 2048 + kv0 + (j ^ (row & 7)) * 8;
      gload_lds16(g, (char*)bufV + c * 16);
    }
  };

  for (int t = 0; t < 4; ++t){
    const int kv0 = kvbase + t * 64;
    __syncthreads();
    stageK(Kh, kv0);
    stageV(kv0);
    __syncthreads();

    f32x4 s[4];
#pragma unroll
    for (int kb = 0; kb < 4; kb++) s[kb] = (f32x4){0.f, 0.f, 0.f, 0.f};
#pragma unroll
    for (int ks = 0; ks < 8; ks++){
      bf16x8 bfr[4];
      const int swz = (((ks * 4 + lg) ^ lr7)) * 8;
#pragma unroll
      for (int kb = 0; kb < 4; kb++)
        bfr[kb] = *(const bf16x8*)(bufK + (kb * 16 + lr) * 256 + swz);
#pragma unroll
      for (int kb = 0; kb < 4; kb++) s[kb] = mfma16(qf[ks], bfr[kb], s[kb]);
      if (split){
#pragma unroll
        for (int kb = 0; kb < 4; kb++) s[kb] = mfma16(qfl[ks], bfr[kb], s[kb]);
      }
    }
    if (split){
      __syncthreads();
      stageK(Kl, kv0);
      __syncthreads();
#pragma unroll
      for (int ks = 0; ks < 8; ks++){
        bf16x8 bfr[4];
        const int swz = (((ks * 4 + lg) ^ lr7)) * 8;
#pragma unroll
        for (int kb = 0; kb < 4; kb++)
          bfr[kb] = *(const bf16x8*)(bufK + (kb * 16 + lr) * 256 + swz);
#pragma unroll
        for (int kb = 0; kb < 4; kb++) s[kb] = mfma16(qf[ks], bfr[kb], s[kb]);
      }
    }

    // ---- online softmax with defer-max ----
#pragma unroll
    for (int kb = 0; kb < 4; kb++)
#pragma unroll
      for (int r = 0; r < 4; r++) s[kb][r] *= scale;

    float pm[4];
#pragma unroll
    for (int r = 0; r < 4; r++)
      pm[r] = fmaxf(fmaxf(s[0][r], s[1][r]), fmaxf(s[2][r], s[3][r]));
#pragma unroll
    for (int m = 1; m < 16; m <<= 1)
#pragma unroll
      for (int r = 0; r < 4; r++) pm[r] = fmaxf(pm[r], __shfl_xor(pm[r], m));

    float g = fmaxf(fmaxf(pm[0] - mrun[0], pm[1] - mrun[1]),
                    fmaxf(pm[2] - mrun[2], pm[3] - mrun[3]));
    if (__any(g > 8.0f)){
#pragma unroll
      for (int r = 0; r < 4; r++){
        float mn = fmaxf(mrun[r], pm[r]);
        float corr = __expf(mrun[r] - mn);
        mrun[r] = mn;
        lpart[r] *= corr;
#pragma unroll
        for (int db = 0; db < 16; db++) accO[db][r] *= corr;
      }
    }
#pragma unroll
    for (int kb = 0; kb < 4; kb++)
#pragma unroll
      for (int r = 0; r < 4; r++){
        float p = __expf(s[kb][r] - mrun[r]);
        lpart[r] += p;
        ldsP[w][(lg * 4 + r) * 72 + kb * 16 + lr] = f2b(p);
      }

    // ---- PV ----
#pragma unroll
    for (int ks2 = 0; ks2 < 2; ++ks2){
      bf16x8 pa = *(const bf16x8*)(ldsP[w] + lr * 72 + ks2 * 32 + lg * 8);
      const int swz = (((ks2 * 4 + lg) ^ lr7)) * 8;
#pragma unroll
      for (int db = 0; db < 16; ++db){
        bf16x8 vb = *(const bf16x8*)(bufV + (db * 16 + lr) * 64 + swz);
        accO[db] = mfma16(pa, vb, accO[db]);
      }
    }
  }

  float lrun[4];
#pragma unroll
  for (int r = 0; r < 4; r++) lrun[r] = lpart[r];
#pragma unroll
  for (int m = 1; m < 16; m <<= 1)
#pragma unroll
    for (int r = 0; r < 4; r++) lrun[r] += __shfl_xor(lrun[r], m);

#pragma unroll
  for (int db = 0; db < 16; db++)
#pragma unroll
    for (int r = 0; r < 4; r++){
      int q = q0 + lg * 4 + r;
      int d = db * 16 + lr;
      Opart[((size_t)((kc * 2 + by) * 2048 + q)) * 256 + d] = accO[db][r];
    }
  if (lr == 0){
#pragma unroll
    for (int r = 0; r < 4; r++){
      int idx = (kc * 2 + by) * 2048 + q0 + lg * 4 + r;
      mlp[idx] = mrun[r];
      mlp[32768 + idx] = lrun[r];
    }
  }
}

// ---------------------------------------------------------------------------
// merge 8 split-K partials
// ---------------------------------------------------------------------------
__global__ __launch_bounds__(256) void merge_k(
    const float* __restrict__ Opart, const float* __restrict__ ml,
    float* __restrict__ outp)
{
  const int w = threadIdx.x >> 6, l = threadIdx.x & 63;
  const int row = blockIdx.x * 4 + w;
  const int b = row >> 11, q = row & 2047;
  float m[8], li[8], M = -3e38f;
#pragma unroll
  for (int kc = 0; kc < 8; kc++){
    int idx = (kc * 2 + b) * 2048 + q;
    m[kc] = ml[idx];
    li[kc] = ml[32768 + idx];
    M = fmaxf(M, m[kc]);
  }
  float L = 0.f, wgt[8];
#pragma unroll
  for (int kc = 0; kc < 8; kc++){ wgt[kc] = __expf(m[kc] - M); L += li[kc] * wgt[kc]; }
  const float invL = 1.f / L;
  f32x4 o = (f32x4){0.f, 0.f, 0.f, 0.f};
#pragma unroll
  for (int kc = 0; kc < 8; kc++){
    f32x4 v = *(const f32x4*)(Opart + ((size_t)((kc * 2 + b) * 2048 + q)) * 256 + l * 4);
#pragma unroll
    for (int i = 0; i < 4; i++) o[i] += v[i] * wgt[kc];
  }
#pragma unroll
  for (int i = 0; i < 4; i++) o[i] *= invL;
  *(f32x4*)(outp + (size_t)row * 256 + l * 4) = o;
}

// ---------------------------------------------------------------------------
// LayerNorm over 256: out = LN(x + res).
// ---------------------------------------------------------------------------
template<int RESF32, int OUTFLAG>
__global__ __launch_bounds__(256) void ln_k(
    const float* __restrict__ x, const void* __restrict__ res,
    const float* __restrict__ g, const float* __restrict__ bb,
    void* __restrict__ outp, const int* __restrict__ flagp)
{
  const int w = threadIdx.x >> 6, l = threadIdx.x & 63;
  const int row = blockIdx.x * 4 + w;
  const size_t off = (size_t)row * 256 + l * 4;
  f32x4 xv = *(const f32x4*)(x + off);
  float v[4];
  if (RESF32){
    f32x4 rv = *(const f32x4*)((const float*)res + off);
#pragma unroll
    for (int i = 0; i < 4; i++) v[i] = xv[i] + rv[i];
  } else {
    const u16* rp = (const u16*)res + off;
#pragma unroll
    for (int i = 0; i < 4; i++) v[i] = xv[i] + b2f(rp[i]);
  }
  float s = 0.f, sq = 0.f;
#pragma unroll
  for (int i = 0; i < 4; i++){ s += v[i]; sq += v[i] * v[i]; }
  for (int m = 1; m < 64; m <<= 1){ s += __shfl_xor(s, m); sq += __shfl_xor(sq, m); }
  const float mean = s * (1.f / 256.f);
  const float var = sq * (1.f / 256.f) - mean * mean;
  const float rstd = rsqrtf(var + 1e-5f);
  float y[4];
#pragma unroll
  for (int i = 0; i < 4; i++) y[i] = (v[i] - mean) * rstd * g[l * 4 + i] + bb[l * 4 + i];
  const bool f32out = OUTFLAG && (*flagp);
  if (f32out){
    f32x4 o;
#pragma unroll
    for (int i = 0; i < 4; i++) o[i] = y[i];
    *(f32x4*)((float*)outp + off) = o;
  } else {
    s16x4 o;
#pragma unroll
    for (int i = 0; i < 4; i++) o[i] = (short)f2b(y[i]);
    *(s16x4*)((u16*)outp + off) = o;
  }
}

// ---------------------------------------------------------------------------
extern "C" void kernel_launch(void* const* d_in, const int* in_sizes, int n_in,
                              void* d_out, int out_size, void* d_ws, size_t ws_size,
                              hipStream_t stream)
{
  (void)in_sizes; (void)n_in; (void)out_size; (void)ws_size;
  char* ws = (char*)d_ws;
  size_t off = 0;
  auto alloc = [&](size_t bytes) -> char* {
    char* p = ws + off;
    off += (bytes + 255) & ~(size_t)255;
    return p;
  };
  int*   flag    = (int*)  alloc(4);
  float* p_scale = (float*)alloc(4);
  float* p_bq    = (float*)alloc(2048 * 4);
  float* p_bk    = (float*)alloc(2048 * 4);
  float* p_bv    = (float*)alloc(2048 * 4);
  float* p_bo    = (float*)alloc(256 * 4);
  float* p_b1    = (float*)alloc(512 * 4);
  float* p_b2    = (float*)alloc(256 * 4);
  float* p_g     = (float*)alloc(256 * 4);
  float* p_b     = (float*)alloc(256 * 4);
  u16* Qc  = (u16*)alloc((size_t)1048576 * 2);
  u16* Qlo = (u16*)alloc((size_t)1048576 * 2);
  u16* Hc  = (u16*)alloc((size_t)1048576 * 2);
  u16* Hlo = (u16*)alloc((size_t)1048576 * 2);
  u16* Ac  = (u16*)alloc((size_t)1048576 * 2);
  u16* wqc = (u16*)alloc((size_t)524288 * 2);
  u16* wkc = (u16*)alloc((size_t)524288 * 2);
  u16* wvc = (u16*)alloc((size_t)524288 * 2);
  u16* woc = (u16*)alloc((size_t)524288 * 2);
  u16* w1c = (u16*)alloc((size_t)131072 * 2);
  u16* w2c = (u16*)alloc((size_t)131072 * 2);
  u16* qbuf = (u16*)alloc((size_t)4096 * 2048 * 2);   // reused: Opart (with kbuf)
  u16* kbuf = (u16*)alloc((size_t)4096 * 2048 * 2);
  u16* vtb  = (u16*)alloc((size_t)4096 * 2048 * 2);   // reused: ml buffer
  u16* ctx  = (u16*)alloc((size_t)4096 * 2048 * 2);
  u16* At   = (u16*)alloc((size_t)1048576 * 2);
  float* attn_o = (float*)alloc((size_t)4096 * 256 * 4);
  float* Am     = (float*)alloc((size_t)4096 * 256 * 4);
  u16* Ad  = (u16*)alloc((size_t)1048576 * 2);
  u16* h1  = (u16*)alloc((size_t)4096 * 512 * 2);
  float* ffb = (float*)alloc((size_t)4096 * 256 * 4);

  detect_kernel<<<1, 256, 0, stream>>>((const u16*)d_in[0], flag);

  ConvJobs J{};
  auto setj = [&](int i, const void* s, void* d, void* d2, int n, int m){
    J.src[i] = s; J.dst[i] = d; J.dst2[i] = d2; J.n[i] = n; J.mode[i] = m;
  };
  setj(0,  d_in[0],  Qc,  Qlo, 1048576, 1);
  setj(1,  d_in[1],  Hc,  Hlo, 1048576, 1);
  setj(2,  d_in[2],  Ac,  nullptr, 1048576, 0);
  setj(3,  d_in[3],  wqc, nullptr, 524288, 0);
  setj(4,  d_in[5],  wkc, nullptr, 524288, 0);
  setj(5,  d_in[7],  wvc, nullptr, 524288, 0);
  setj(6,  d_in[9],  woc, nullptr, 524288, 0);
  setj(7,  d_in[14], w1c, nullptr, 131072, 0);
  setj(8,  d_in[16], w2c, nullptr, 131072, 0);
  setj(9,  d_in[4],  p_bq, nullptr, 2048, 2);
  setj(10, d_in[6],  p_bk, nullptr, 2048, 2);
  setj(11, d_in[8],  p_bv, nullptr, 2048, 2);
  setj(12, d_in[10], p_bo, nullptr, 256, 2);
  setj(13, d_in[15], p_b1, nullptr, 512, 2);
  setj(14, d_in[17], p_b2, nullptr, 256, 2);
  setj(15, d_in[12], p_g,  nullptr, 256, 2);
  setj(16, d_in[13], p_b,  nullptr, 256, 2);
  setj(17, d_in[11], p_scale, nullptr, 1, 2);
  convert_all<<<dim3(64, 18), 256, 0, stream>>>(J, flag);

  // QKV projections (M=4096, N=2048, K=256)
  gemm_bt<0, false><<<dim3(32, 16), 256, 0, stream>>>(Qc, wqc, p_bq, qbuf, 4096, 2048, 256);
  gemm_bt<0, false><<<dim3(32, 16), 256, 0, stream>>>(Hc, wkc, p_bk, kbuf, 4096, 2048, 256);
  gemm_bt<2, false><<<dim3(32, 16), 256, 0, stream>>>(Ac, wvc, p_bv, vtb,  4096, 2048, 256);
  transpose_k<<<dim3(32, 4, 2), 256, 0, stream>>>(Ac, At);

  // MHA flash (XCD-aware 1D grid, 8 waves x 16 q-rows, dbuf K/V + counted vmcnt)
  flash_mha<<<dim3(256), 512, 0, stream>>>(qbuf, kbuf, vtb, ctx);

  // branch2 flash, split-K into 8 chunks
  float* Opart = (float*)qbuf;      // 32 MB spans qbuf+kbuf (contiguous)
  float* mlbuf = (float*)vtb;
  flash_b2<<<dim3(32, 2, 8), 256, 0, stream>>>(Qc, Qlo, Hc, Hlo, At,
                                               Opart, mlbuf, p_scale, flag);
  merge_k<<<1024, 256, 0, stream>>>(Opart, mlbuf, attn_o);

  // output projection + LN + FFN + LN  (64x64-tile GEMMs fill the grid)
  gemm_bt64<1, false><<<dim3(64, 4), 256, 0, stream>>>(ctx, woc, p_bo, Am, 4096, 256, 2048);
  ln_k<1, 0><<<1024, 256, 0, stream>>>(Am, attn_o, p_g, p_b, Ad, flag);
  gemm_bt64<0, true ><<<dim3(64, 8), 256, 0, stream>>>(Ad, w1c, p_b1, h1, 4096, 512, 256);
  gemm_bt64<1, false><<<dim3(64, 4), 256, 0, stream>>>(h1, w2c, p_b2, ffb, 4096, 256, 512);
  ln_k<0, 1><<<1024, 256, 0, stream>>>(ffb, Ad, p_g, p_b, d_out, flag);
}

// Round 15
// 270.356 us; speedup vs baseline: 1.0638x; 1.0638x over previous
//
#include <hip/hip_runtime.h>
#include <cstdint>
#include <cstddef>

// ---------------------------------------------------------------------------
// DeductionNetworkSingleLayer.  R15 = R14 + tail fusions:
//  (1) QKV projections -> single gemm_qkv launch (blockIdx.z selects job)
//  (2) merge_k + ln_k<1,0> -> ln_merge (branch2 merge never hits HBM)
// flash_mha unchanged from R14 (116us; verified floor of this decomposition).
// ---------------------------------------------------------------------------

typedef unsigned short u16;
typedef __attribute__((ext_vector_type(8))) short bf16x8;
typedef __attribute__((ext_vector_type(4))) short s16x4;
typedef __attribute__((ext_vector_type(4))) float f32x4;

__device__ __forceinline__ float b2f(u16 u){
  union { unsigned int i; float f; } v; v.i = ((unsigned int)u) << 16; return v.f;
}
__device__ __forceinline__ u16 f2b(float f){
  union { float f; unsigned int i; } v; v.f = f;
  unsigned int u = v.i;
  unsigned int r = (u + 0x7FFFu + ((u >> 16) & 1u)) >> 16;
  return (u16)r;
}
__device__ __forceinline__ f32x4 mfma16(bf16x8 a, bf16x8 b, f32x4 c){
  return __builtin_amdgcn_mfma_f32_16x16x32_bf16(a, b, c, 0, 0, 0);
}
__device__ __forceinline__ void gload_lds16(const void* g, void* l){
  __builtin_amdgcn_global_load_lds(
      (const __attribute__((address_space(1))) unsigned int*)g,
      (__attribute__((address_space(3))) unsigned int*)l, 16, 0, 0);
}

// ---------------------------------------------------------------------------
__global__ void detect_kernel(const u16* __restrict__ q, int* __restrict__ flag){
  __shared__ int cnt;
  if (threadIdx.x == 0) cnt = 0;
  __syncthreads();
  int c = 0;
  for (int i = threadIdx.x; i < 2048; i += 256){
    u16 u = q[i];
    int e = (u >> 7) & 0xFF;
    if (e >= 140) c++;
  }
  atomicAdd(&cnt, c);
  __syncthreads();
  if (threadIdx.x == 0) *flag = (cnt > 64) ? 1 : 0;   // 1 => inputs are fp32
}

// ---------------------------------------------------------------------------
struct ConvJobs {
  const void* src[18];
  void*       dst[18];
  void*       dst2[18];
  int         n[18];
  int         mode[18];   // 0 = bf16 hi, 1 = bf16 hi+lo, 2 = f32 out
};

__global__ void convert_all(ConvJobs J, const int* __restrict__ flag){
  const int j = blockIdx.y;
  const int n = J.n[j];
  const int mode = J.mode[j];
  const int isf = *flag;
  for (int i = blockIdx.x * blockDim.x + threadIdx.x; i < n; i += gridDim.x * blockDim.x){
    if (mode == 2){
      float f = isf ? ((const float*)J.src[j])[i] : b2f(((const u16*)J.src[j])[i]);
      ((float*)J.dst[j])[i] = f;
    } else {
      u16 hi, lo = 0;
      if (isf){
        float f = ((const float*)J.src[j])[i];
        hi = f2b(f);
        if (mode == 1) lo = f2b(f - b2f(hi));
      } else {
        hi = ((const u16*)J.src[j])[i];
      }
      ((u16*)J.dst[j])[i] = hi;
      if (mode == 1) ((u16*)J.dst2[j])[i] = lo;
    }
  }
}

// ---------------------------------------------------------------------------
// gemm_qkv: all three QKV projections in ONE launch.  grid (32,16,3);
// z selects {X,W,bias,out,store-mode}.  M=4096,N=2048,K=256 fixed.
// z==2 (V) stores transposed-per-head v^T; else bf16 row-major.
// Body identical to the verified gemm_bt 128x128 swizzled structure.
// ---------------------------------------------------------------------------
__global__ __launch_bounds__(256) void gemm_qkv(
    const u16* __restrict__ Qc, const u16* __restrict__ Hc, const u16* __restrict__ Ac,
    const u16* __restrict__ wq, const u16* __restrict__ wk, const u16* __restrict__ wv,
    const float* __restrict__ bq, const float* __restrict__ bk, const float* __restrict__ bv,
    u16* __restrict__ qo, u16* __restrict__ ko, u16* __restrict__ vo)
{
  const int z = blockIdx.z;
  const u16* X = (z == 0) ? Qc : (z == 1) ? Hc : Ac;
  const u16* W = (z == 0) ? wq : (z == 1) ? wk : wv;
  const float* bias = (z == 0) ? bq : (z == 1) ? bk : bv;
  u16* outp = (z == 0) ? qo : (z == 1) ? ko : vo;
  const bool vstore = (z == 2);
  const int K = 256, N = 2048;

  __shared__ __align__(16) u16 lx[128 * 64];
  __shared__ __align__(16) u16 lw[128 * 64];
  const int tid = threadIdx.x;
  const int l = tid & 63, w = tid >> 6;
  const int lg = l >> 4, lr = l & 15;
  const int wr = w >> 1, wc = w & 1;
  const int m0 = blockIdx.x * 128;
  const int n0 = blockIdx.y * 128;

  f32x4 acc[4][4];
#pragma unroll
  for (int mi = 0; mi < 4; mi++)
#pragma unroll
    for (int ni = 0; ni < 4; ni++) acc[mi][ni] = (f32x4){0.f, 0.f, 0.f, 0.f};

  for (int kt = 0; kt < 4; ++kt){
    __syncthreads();
#pragma unroll
    for (int it = 0; it < 4; ++it){
      int c = it * 256 + tid;
      int row = c >> 3, j = c & 7;
      int sj = (j ^ (row & 7)) * 8;
      const u16* gx = X + (size_t)(m0 + row) * K + kt * 64 + sj;
      gload_lds16(gx, (char*)lx + c * 16);
      const u16* gw = W + (size_t)(n0 + row) * K + kt * 64 + sj;
      gload_lds16(gw, (char*)lw + c * 16);
    }
    __syncthreads();
#pragma unroll
    for (int ks = 0; ks < 2; ++ks){
      bf16x8 af[4], bfv[4];
      const int swz = ((ks * 4 + lg) ^ (lr & 7)) * 8;
#pragma unroll
      for (int mi = 0; mi < 4; mi++)
        af[mi] = *(const bf16x8*)(lx + (wr * 64 + mi * 16 + lr) * 64 + swz);
#pragma unroll
      for (int ni = 0; ni < 4; ni++)
        bfv[ni] = *(const bf16x8*)(lw + (wc * 64 + ni * 16 + lr) * 64 + swz);
#pragma unroll
      for (int mi = 0; mi < 4; mi++)
#pragma unroll
        for (int ni = 0; ni < 4; ni++)
          acc[mi][ni] = mfma16(af[mi], bfv[ni], acc[mi][ni]);
    }
  }

#pragma unroll
  for (int mi = 0; mi < 4; mi++)
#pragma unroll
    for (int ni = 0; ni < 4; ni++){
      const int gr0 = m0 + wr * 64 + mi * 16 + lg * 4;
      const int gc  = n0 + wc * 64 + ni * 16 + lr;
      const float bv2 = bias[gc];
      if (vstore){
        const int b = gr0 >> 11, sk0 = gr0 & 2047;
        const int h = gc >> 8,  d   = gc & 255;
        s16x4 pk;
#pragma unroll
        for (int r = 0; r < 4; r++) pk[r] = (short)f2b(acc[mi][ni][r] + bv2);
        *(s16x4*)(outp + ((size_t)((b << 3) + h) * 256 + d) * 2048 + sk0) = pk;
      } else {
#pragma unroll
        for (int r = 0; r < 4; r++)
          outp[(size_t)(gr0 + r) * N + gc] = f2b(acc[mi][ni][r] + bv2);
      }
    }
}

// ---------------------------------------------------------------------------
// GEMM 64x64 tile variant: fills the grid for small-N GEMMs (wo, w1, w2).
// ---------------------------------------------------------------------------
template<int STORE, bool RELU>
__global__ __launch_bounds__(256) void gemm_bt64(
    const u16* __restrict__ X, const u16* __restrict__ W,
    const float* __restrict__ bias, void* __restrict__ outp,
    int M, int N, int K)
{
  __shared__ __align__(16) u16 lx[64 * 64];
  __shared__ __align__(16) u16 lw[64 * 64];
  const int tid = threadIdx.x;
  const int l = tid & 63, w = tid >> 6;
  const int lg = l >> 4, lr = l & 15;
  const int wr = w >> 1, wc = w & 1;
  const int m0 = blockIdx.x * 64;
  const int n0 = blockIdx.y * 64;

  f32x4 acc[2][2];
#pragma unroll
  for (int mi = 0; mi < 2; mi++)
#pragma unroll
    for (int ni = 0; ni < 2; ni++) acc[mi][ni] = (f32x4){0.f, 0.f, 0.f, 0.f};

  const int nkt = K >> 6;
  for (int kt = 0; kt < nkt; ++kt){
    __syncthreads();
#pragma unroll
    for (int it = 0; it < 2; ++it){
      int c = it * 256 + tid;
      int row = c >> 3, j = c & 7;
      int sj = (j ^ (row & 7)) * 8;
      const u16* gx = X + (size_t)(m0 + row) * K + kt * 64 + sj;
      gload_lds16(gx, (char*)lx + c * 16);
      const u16* gw = W + (size_t)(n0 + row) * K + kt * 64 + sj;
      gload_lds16(gw, (char*)lw + c * 16);
    }
    __syncthreads();
#pragma unroll
    for (int ks = 0; ks < 2; ++ks){
      bf16x8 af[2], bfv[2];
      const int swz = ((ks * 4 + lg) ^ (lr & 7)) * 8;
#pragma unroll
      for (int mi = 0; mi < 2; mi++)
        af[mi] = *(const bf16x8*)(lx + (wr * 32 + mi * 16 + lr) * 64 + swz);
#pragma unroll
      for (int ni = 0; ni < 2; ni++)
        bfv[ni] = *(const bf16x8*)(lw + (wc * 32 + ni * 16 + lr) * 64 + swz);
#pragma unroll
      for (int mi = 0; mi < 2; mi++)
#pragma unroll
        for (int ni = 0; ni < 2; ni++)
          acc[mi][ni] = mfma16(af[mi], bfv[ni], acc[mi][ni]);
    }
  }

#pragma unroll
  for (int mi = 0; mi < 2; mi++)
#pragma unroll
    for (int ni = 0; ni < 2; ni++){
      const int gr0 = m0 + wr * 32 + mi * 16 + lg * 4;
      const int gc  = n0 + wc * 32 + ni * 16 + lr;
      const float bv = bias ? bias[gc] : 0.f;
#pragma unroll
      for (int r = 0; r < 4; r++){
        float v = acc[mi][ni][r] + bv;
        if (RELU) v = fmaxf(v, 0.f);
        size_t idx = (size_t)(gr0 + r) * N + gc;
        if (STORE == 0) ((u16*)outp)[idx] = f2b(v);
        else            ((float*)outp)[idx] = v;
      }
    }
}

// ---------------------------------------------------------------------------
// 64x64 bf16 transpose: At[b][d][sk] = Ac[b][sk][d]
// ---------------------------------------------------------------------------
__global__ __launch_bounds__(256) void transpose_k(const u16* __restrict__ src, u16* __restrict__ dst){
  __shared__ u16 t[64][72];
  const int b   = blockIdx.z;
  const int sk0 = blockIdx.x * 64;
  const int d0  = blockIdx.y * 64;
  const int tid = threadIdx.x;
  union U8 { bf16x8 v; u16 e[8]; };
#pragma unroll
  for (int half = 0; half < 2; ++half){
    int c = half * 256 + tid;
    int r = c >> 3, c8 = (c & 7) * 8;
    U8 u; u.v = *(const bf16x8*)(src + ((size_t)b * 2048 + sk0 + r) * 256 + d0 + c8);
#pragma unroll
    for (int i = 0; i < 8; i++) t[r][c8 + i] = u.e[i];
  }
  __syncthreads();
#pragma unroll
  for (int half = 0; half < 2; ++half){
    int c = half * 256 + tid;
    int dr = c >> 3, s8 = (c & 7) * 8;
    U8 u;
#pragma unroll
    for (int i = 0; i < 8; i++) u.e[i] = t[s8 + i][dr];
    *(bf16x8*)(dst + ((size_t)b * 256 + d0 + dr) * 2048 + sk0 + s8) = u.v;
  }
}

// ---------------------------------------------------------------------------
// flash_mha: R14 verified (116us).  512 threads (8 waves), 16 q-rows/wave,
// double-buffered K/V (144KB LDS), 2-tile-deep prefetch, counted vmcnt(8) +
// raw s_barrier.  1D grid 256, XCD-aware decode (xcd=bid&7 owns 2 heads).
// ---------------------------------------------------------------------------
__global__ __launch_bounds__(512, 2) void flash_mha(
    const u16* __restrict__ Qp, const u16* __restrict__ Kp,
    const u16* __restrict__ Vt, u16* __restrict__ outp)
{
  __shared__ __align__(16) u16 bufK[2][64 * 256];   // 64KB
  __shared__ __align__(16) u16 bufV[2][256 * 64];   // 64KB
  __shared__ __align__(16) u16 ldsP[8][16 * 64];    // 16KB (swz)
  const int tid = threadIdx.x, l = tid & 63, w = tid >> 6;
  const int lg = l >> 4, lr = l & 15;
  const int lr7 = lr & 7;
  const int bid = blockIdx.x;
  const int xcd = bid & 7;
  const int slot = bid >> 3;
  const int by = xcd * 2 + (slot >> 4);
  const int qt = slot & 15;
  const size_t qkbase = ((size_t)(by >> 3) * 2048) * 2048 + (size_t)(by & 7) * 256;
  const size_t vbase  = (size_t)by * (256 * 2048);
  const int q0 = qt * 128 + w * 16;

  bf16x8 qf[8];
#pragma unroll
  for (int ks = 0; ks < 8; ks++)
    qf[ks] = *(const bf16x8*)(Qp + qkbase +
        (size_t)(q0 + lr) * 2048 + ks * 32 + lg * 8);

  float mrun[4], lpart[4];
#pragma unroll
  for (int r = 0; r < 4; r++){ mrun[r] = -3e38f; lpart[r] = 0.f; }
  f32x4 accO[16];
#pragma unroll
  for (int db = 0; db < 16; db++) accO[db] = (f32x4){0.f, 0.f, 0.f, 0.f};

  auto stageK = [&](int kv0, u16* dst){
#pragma unroll
    for (int it = 0; it < 4; ++it){
      int c = it * 512 + tid;
      int row = c >> 5, j = c & 31;
      const u16* g = Kp + qkbase + (size_t)(kv0 + row) * 2048 + (j ^ (row & 7)) * 8;
      gload_lds16(g, (char*)dst + c * 16);
    }
  };
  auto stageV = [&](int kv0, u16* dst){
#pragma unroll
    for (int it = 0; it < 4; ++it){
      int c = it * 512 + tid;
      int row = c >> 3, j = c & 7;
      const u16* g = Vt + vbase + (size_t)row * 2048 + kv0 + (j ^ (row & 7)) * 8;
      gload_lds16(g, (char*)dst + c * 16);
    }
  };

  stageK(0,  bufK[0]); stageV(0,  bufV[0]);
  stageK(64, bufK[1]); stageV(64, bufV[1]);

  for (int t = 0; t < 32; ++t){
    const int kv0 = t * 64;
    const int cur = t & 1;
    if (t < 31) asm volatile("s_waitcnt vmcnt(8)" ::: "memory");
    else        asm volatile("s_waitcnt vmcnt(0)" ::: "memory");
    asm volatile("s_barrier" ::: "memory");

    f32x4 s[4];
#pragma unroll
    for (int kb = 0; kb < 4; kb++) s[kb] = (f32x4){0.f, 0.f, 0.f, 0.f};

    __builtin_amdgcn_s_setprio(1);
#pragma unroll
    for (int ks = 0; ks < 8; ks++){
      bf16x8 bfr[4];
      const int swz = (((ks * 4 + lg) ^ lr7)) * 8;
#pragma unroll
      for (int kb = 0; kb < 4; kb++)
        bfr[kb] = *(const bf16x8*)(bufK[cur] + (kb * 16 + lr) * 256 + swz);
#pragma unroll
      for (int kb = 0; kb < 4; kb++)
        s[kb] = mfma16(qf[ks], bfr[kb], s[kb]);
    }
    __builtin_amdgcn_s_setprio(0);

    float pm[4];
#pragma unroll
    for (int kb = 0; kb < 4; kb++)
#pragma unroll
      for (int r = 0; r < 4; r++) s[kb][r] *= 0.0625f;
#pragma unroll
    for (int r = 0; r < 4; r++)
      pm[r] = fmaxf(fmaxf(s[0][r], s[1][r]), fmaxf(s[2][r], s[3][r]));
#pragma unroll
    for (int m = 1; m < 16; m <<= 1)
#pragma unroll
      for (int r = 0; r < 4; r++) pm[r] = fmaxf(pm[r], __shfl_xor(pm[r], m));

    float gmax = fmaxf(fmaxf(pm[0] - mrun[0], pm[1] - mrun[1]),
                       fmaxf(pm[2] - mrun[2], pm[3] - mrun[3]));
    if (__any(gmax > 8.0f)){
#pragma unroll
      for (int r = 0; r < 4; r++){
        float mn = fmaxf(mrun[r], pm[r]);
        float corr = __expf(mrun[r] - mn);
        mrun[r] = mn;
        lpart[r] *= corr;
#pragma unroll
        for (int db = 0; db < 16; db++) accO[db][r] *= corr;
      }
    }
#pragma unroll
    for (int kb = 0; kb < 4; kb++)
#pragma unroll
      for (int r = 0; r < 4; r++){
        float p = __expf(s[kb][r] - mrun[r]);
        lpart[r] += p;
        const int row = lg * 4 + r;
        ldsP[w][(row << 6) + (((kb * 2 + (lr >> 3)) ^ (row & 7)) << 3) + (lr & 7)] = f2b(p);
      }

    __builtin_amdgcn_s_setprio(1);
#pragma unroll
    for (int ks2 = 0; ks2 < 2; ++ks2){
      bf16x8 pa = *(const bf16x8*)(ldsP[w] + (lr << 6) + (((ks2 * 4 + lg) ^ lr7) << 3));
      const int swz = (((ks2 * 4 + lg) ^ lr7)) * 8;
#pragma unroll
      for (int db = 0; db < 16; ++db){
        bf16x8 vb = *(const bf16x8*)(bufV[cur] + (db * 16 + lr) * 64 + swz);
        accO[db] = mfma16(pa, vb, accO[db]);
      }
    }
    __builtin_amdgcn_s_setprio(0);

    asm volatile("s_barrier" ::: "memory");
    if (t + 2 < 32){
      stageK(kv0 + 128, bufK[cur]);
      stageV(kv0 + 128, bufV[cur]);
    }
  }

  float lrun[4];
#pragma unroll
  for (int r = 0; r < 4; r++) lrun[r] = lpart[r];
#pragma unroll
  for (int m = 1; m < 16; m <<= 1)
#pragma unroll
    for (int r = 0; r < 4; r++) lrun[r] += __shfl_xor(lrun[r], m);
  float inv[4];
#pragma unroll
  for (int r = 0; r < 4; r++) inv[r] = 1.f / lrun[r];
#pragma unroll
  for (int db = 0; db < 16; db++)
#pragma unroll
    for (int r = 0; r < 4; r++){
      float v = accO[db][r] * inv[r];
      int q = q0 + lg * 4 + r;
      int d = db * 16 + lr;
      outp[((size_t)(by >> 3) * 2048 + q) * 2048 + (size_t)(by & 7) * 256 + d] = f2b(v);
    }
}

// ---------------------------------------------------------------------------
// flash_b2: split-K branch2, grid (32,2,8).
// ---------------------------------------------------------------------------
__global__ __launch_bounds__(256) void flash_b2(
    const u16* __restrict__ Qh, const u16* __restrict__ Ql,
    const u16* __restrict__ Kh, const u16* __restrict__ Kl,
    const u16* __restrict__ Vt,
    float* __restrict__ Opart, float* __restrict__ mlp,
    const float* __restrict__ p_scale, const int* __restrict__ flagp)
{
  __shared__ __align__(16) u16 bufK[64 * 256];
  __shared__ __align__(16) u16 bufV[256 * 64];
  __shared__ __align__(16) u16 ldsP[4][16 * 72];
  const int tid = threadIdx.x, l = tid & 63, w = tid >> 6;
  const int lg = l >> 4, lr = l & 15;
  const int lr7 = lr & 7;
  const int by = blockIdx.y, qt = blockIdx.x, kc = blockIdx.z;
  const size_t qkbase = (size_t)by * (2048 * 256);
  const size_t vbase  = (size_t)by * (256 * 2048);
  const float scale = *p_scale;
  const int split = *flagp;
  const int kvbase = kc * 256;
  const int q0 = qt * 64 + w * 16;

  bf16x8 qf[8], qfl[8];
#pragma unroll
  for (int ks = 0; ks < 8; ks++)
    qf[ks] = *(const bf16x8*)(Qh + qkbase + (size_t)(q0 + lr) * 256 + ks * 32 + lg * 8);
  if (split){
#pragma unroll
    for (int ks = 0; ks < 8; ks++)
      qfl[ks] = *(const bf16x8*)(Ql + qkbase + (size_t)(q0 + lr) * 256 + ks * 32 + lg * 8);
  } else {
#pragma unroll
    for (int ks = 0; ks < 8; ks++) qfl[ks] = qf[ks];
  }

  float mrun[4], lpart[4];
#pragma unroll
  for (int r = 0; r < 4; r++){ mrun[r] = -3e38f; lpart[r] = 0.f; }
  f32x4 accO[16];
#pragma unroll
  for (int db = 0; db < 16; db++) accO[db] = (f32x4){0.f, 0.f, 0.f, 0.f};

  auto stageK = [&](const u16* __restrict__ src, int kv0){
#pragma unroll
    for (int it = 0; it < 8; ++it){
      int c = it * 256 + tid;
      int row = c >> 5, j = c & 31;
      const u16* g = src + qkbase + (size_t)(kv0 + row) * 256 + (j ^ (row & 7)) * 8;
      gload_lds16(g, (char*)bufK + c * 16);
    }
  };
  auto stageV = [&](int kv0){
#pragma unroll
    for (int it = 0; it < 8; ++it){
      int c = it * 256 + tid;
      int row = c >> 3, j = c & 7;
      const u16* g = Vt + vbase + (size_t)row * 2048 + kv0 + (j ^ (row & 7)) * 8;
      gload_lds16(g, (char*)bufV + c * 16);
    }
  };

  for (int t = 0; t < 4; ++t){
    const int kv0 = kvbase + t * 64;
    __syncthreads();
    stageK(Kh, kv0);
    stageV(kv0);
    __syncthreads();

    f32x4 s[4];
#pragma unroll
    for (int kb = 0; kb < 4; kb++) s[kb] = (f32x4){0.f, 0.f, 0.f, 0.f};
#pragma unroll
    for (int ks = 0; ks < 8; ks++){
      bf16x8 bfr[4];
      const int swz = (((ks * 4 + lg) ^ lr7)) * 8;
#pragma unroll
      for (int kb = 0; kb < 4; kb++)
        bfr[kb] = *(const bf16x8*)(bufK + (kb * 16 + lr) * 256 + swz);
#pragma unroll
      for (int kb = 0; kb < 4; kb++) s[kb] = mfma16(qf[ks], bfr[kb], s[kb]);
      if (split){
#pragma unroll
        for (int kb = 0; kb < 4; kb++) s[kb] = mfma16(qfl[ks], bfr[kb], s[kb]);
      }
    }
    if (split){
      __syncthreads();
      stageK(Kl, kv0);
      __syncthreads();
#pragma unroll
      for (int ks = 0; ks < 8; ks++){
        bf16x8 bfr[4];
        const int swz = (((ks * 4 + lg) ^ lr7)) * 8;
#pragma unroll
        for (int kb = 0; kb < 4; kb++)
          bfr[kb] = *(const bf16x8*)(bufK + (kb * 16 + lr) * 256 + swz);
#pragma unroll
        for (int kb = 0; kb < 4; kb++) s[kb] = mfma16(qf[ks], bfr[kb], s[kb]);
      }
    }

#pragma unroll
    for (int kb = 0; kb < 4; kb++)
#pragma unroll
      for (int r = 0; r < 4; r++) s[kb][r] *= scale;

    float pm[4];
#pragma unroll
    for (int r = 0; r < 4; r++)
      pm[r] = fmaxf(fmaxf(s[0][r], s[1][r]), fmaxf(s[2][r], s[3][r]));
#pragma unroll
    for (int m = 1; m < 16; m <<= 1)
#pragma unroll
      for (int r = 0; r < 4; r++) pm[r] = fmaxf(pm[r], __shfl_xor(pm[r], m));

    float g = fmaxf(fmaxf(pm[0] - mrun[0], pm[1] - mrun[1]),
                    fmaxf(pm[2] - mrun[2], pm[3] - mrun[3]));
    if (__any(g > 8.0f)){
#pragma unroll
      for (int r = 0; r < 4; r++){
        float mn = fmaxf(mrun[r], pm[r]);
        float corr = __expf(mrun[r] - mn);
        mrun[r] = mn;
        lpart[r] *= corr;
#pragma unroll
        for (int db = 0; db < 16; db++) accO[db][r] *= corr;
      }
    }
#pragma unroll
    for (int kb = 0; kb < 4; kb++)
#pragma unroll
      for (int r = 0; r < 4; r++){
        float p = __expf(s[kb][r] - mrun[r]);
        lpart[r] += p;
        ldsP[w][(lg * 4 + r) * 72 + kb * 16 + lr] = f2b(p);
      }

#pragma unroll
    for (int ks2 = 0; ks2 < 2; ++ks2){
      bf16x8 pa = *(const bf16x8*)(ldsP[w] + lr * 72 + ks2 * 32 + lg * 8);
      const int swz = (((ks2 * 4 + lg) ^ lr7)) * 8;
#pragma unroll
      for (int db = 0; db < 16; ++db){
        bf16x8 vb = *(const bf16x8*)(bufV + (db * 16 + lr) * 64 + swz);
        accO[db] = mfma16(pa, vb, accO[db]);
      }
    }
  }

  float lrun[4];
#pragma unroll
  for (int r = 0; r < 4; r++) lrun[r] = lpart[r];
#pragma unroll
  for (int m = 1; m < 16; m <<= 1)
#pragma unroll
    for (int r = 0; r < 4; r++) lrun[r] += __shfl_xor(lrun[r], m);

#pragma unroll
  for (int db = 0; db < 16; db++)
#pragma unroll
    for (int r = 0; r < 4; r++){
      int q = q0 + lg * 4 + r;
      int d = db * 16 + lr;
      Opart[((size_t)((kc * 2 + by) * 2048 + q)) * 256 + d] = accO[db][r];
    }
  if (lr == 0){
#pragma unroll
    for (int r = 0; r < 4; r++){
      int idx = (kc * 2 + by) * 2048 + q0 + lg * 4 + r;
      mlp[idx] = mrun[r];
      mlp[32768 + idx] = lrun[r];
    }
  }
}

// ---------------------------------------------------------------------------
// ln_merge: fused (merge 8 split-K partials) + (LN(Am + merged) -> Ad bf16).
// One wave per row; 4 rows/block; 1024 blocks.  Math identical to the old
// merge_k followed by ln_k<1,0>.
// ---------------------------------------------------------------------------
__global__ __launch_bounds__(256) void ln_merge(
    const float* __restrict__ Opart, const float* __restrict__ ml,
    const float* __restrict__ Am,
    const float* __restrict__ g, const float* __restrict__ bb,
    u16* __restrict__ outp)
{
  const int w = threadIdx.x >> 6, l = threadIdx.x & 63;
  const int row = blockIdx.x * 4 + w;          // b*2048 + q
  const int b = row >> 11, q = row & 2047;
  float m[8], li[8], M = -3e38f;
#pragma unroll
  for (int kc = 0; kc < 8; kc++){
    int idx = (kc * 2 + b) * 2048 + q;
    m[kc] = ml[idx];
    li[kc] = ml[32768 + idx];
    M = fmaxf(M, m[kc]);
  }
  float L = 0.f, wgt[8];
#pragma unroll
  for (int kc = 0; kc < 8; kc++){ wgt[kc] = __expf(m[kc] - M); L += li[kc] * wgt[kc]; }
  const float invL = 1.f / L;
  f32x4 o = (f32x4){0.f, 0.f, 0.f, 0.f};
#pragma unroll
  for (int kc = 0; kc < 8; kc++){
    f32x4 v = *(const f32x4*)(Opart + ((size_t)((kc * 2 + b) * 2048 + q)) * 256 + l * 4);
#pragma unroll
    for (int i = 0; i < 4; i++) o[i] += v[i] * wgt[kc];
  }
  const size_t off = (size_t)row * 256 + l * 4;
  f32x4 xv = *(const f32x4*)(Am + off);
  float v[4];
#pragma unroll
  for (int i = 0; i < 4; i++) v[i] = xv[i] + o[i] * invL;

  float s = 0.f, sq = 0.f;
#pragma unroll
  for (int i = 0; i < 4; i++){ s += v[i]; sq += v[i] * v[i]; }
  for (int mm = 1; mm < 64; mm <<= 1){ s += __shfl_xor(s, mm); sq += __shfl_xor(sq, mm); }
  const float mean = s * (1.f / 256.f);
  const float var = sq * (1.f / 256.f) - mean * mean;
  const float rstd = rsqrtf(var + 1e-5f);
  s16x4 ov;
#pragma unroll
  for (int i = 0; i < 4; i++)
    ov[i] = (short)f2b((v[i] - mean) * rstd * g[l * 4 + i] + bb[l * 4 + i]);
  *(s16x4*)(outp + off) = ov;
}

// ---------------------------------------------------------------------------
// LayerNorm over 256: out = LN(x + res).  (final LN only)
// ---------------------------------------------------------------------------
template<int RESF32, int OUTFLAG>
__global__ __launch_bounds__(256) void ln_k(
    const float* __restrict__ x, const void* __restrict__ res,
    const float* __restrict__ g, const float* __restrict__ bb,
    void* __restrict__ outp, const int* __restrict__ flagp)
{
  const int w = threadIdx.x >> 6, l = threadIdx.x & 63;
  const int row = blockIdx.x * 4 + w;
  const size_t off = (size_t)row * 256 + l * 4;
  f32x4 xv = *(const f32x4*)(x + off);
  float v[4];
  if (RESF32){
    f32x4 rv = *(const f32x4*)((const float*)res + off);
#pragma unroll
    for (int i = 0; i < 4; i++) v[i] = xv[i] + rv[i];
  } else {
    const u16* rp = (const u16*)res + off;
#pragma unroll
    for (int i = 0; i < 4; i++) v[i] = xv[i] + b2f(rp[i]);
  }
  float s = 0.f, sq = 0.f;
#pragma unroll
  for (int i = 0; i < 4; i++){ s += v[i]; sq += v[i] * v[i]; }
  for (int m = 1; m < 64; m <<= 1){ s += __shfl_xor(s, m); sq += __shfl_xor(sq, m); }
  const float mean = s * (1.f / 256.f);
  const float var = sq * (1.f / 256.f) - mean * mean;
  const float rstd = rsqrtf(var + 1e-5f);
  float y[4];
#pragma unroll
  for (int i = 0; i < 4; i++) y[i] = (v[i] - mean) * rstd * g[l * 4 + i] + bb[l * 4 + i];
  const bool f32out = OUTFLAG && (*flagp);
  if (f32out){
    f32x4 o;
#pragma unroll
    for (int i = 0; i < 4; i++) o[i] = y[i];
    *(f32x4*)((float*)outp + off) = o;
  } else {
    s16x4 o;
#pragma unroll
    for (int i = 0; i < 4; i++) o[i] = (short)f2b(y[i]);
    *(s16x4*)((u16*)outp + off) = o;
  }
}

// ---------------------------------------------------------------------------
extern "C" void kernel_launch(void* const* d_in, const int* in_sizes, int n_in,
                              void* d_out, int out_size, void* d_ws, size_t ws_size,
                              hipStream_t stream)
{
  (void)in_sizes; (void)n_in; (void)out_size; (void)ws_size;
  char* ws = (char*)d_ws;
  size_t off = 0;
  auto alloc = [&](size_t bytes) -> char* {
    char* p = ws + off;
    off += (bytes + 255) & ~(size_t)255;
    return p;
  };
  int*   flag    = (int*)  alloc(4);
  float* p_scale = (float*)alloc(4);
  float* p_bq    = (float*)alloc(2048 * 4);
  float* p_bk    = (float*)alloc(2048 * 4);
  float* p_bv    = (float*)alloc(2048 * 4);
  float* p_bo    = (float*)alloc(256 * 4);
  float* p_b1    = (float*)alloc(512 * 4);
  float* p_b2    = (float*)alloc(256 * 4);
  float* p_g     = (float*)alloc(256 * 4);
  float* p_b     = (float*)alloc(256 * 4);
  u16* Qc  = (u16*)alloc((size_t)1048576 * 2);
  u16* Qlo = (u16*)alloc((size_t)1048576 * 2);
  u16* Hc  = (u16*)alloc((size_t)1048576 * 2);
  u16* Hlo = (u16*)alloc((size_t)1048576 * 2);
  u16* Ac  = (u16*)alloc((size_t)1048576 * 2);
  u16* wqc = (u16*)alloc((size_t)524288 * 2);
  u16* wkc = (u16*)alloc((size_t)524288 * 2);
  u16* wvc = (u16*)alloc((size_t)524288 * 2);
  u16* woc = (u16*)alloc((size_t)524288 * 2);
  u16* w1c = (u16*)alloc((size_t)131072 * 2);
  u16* w2c = (u16*)alloc((size_t)131072 * 2);
  u16* qbuf = (u16*)alloc((size_t)4096 * 2048 * 2);   // reused: Opart (with kbuf)
  u16* kbuf = (u16*)alloc((size_t)4096 * 2048 * 2);
  u16* vtb  = (u16*)alloc((size_t)4096 * 2048 * 2);   // reused: ml buffer
  u16* ctx  = (u16*)alloc((size_t)4096 * 2048 * 2);
  u16* At   = (u16*)alloc((size_t)1048576 * 2);
  float* attn_o = (float*)alloc((size_t)4096 * 256 * 4);   // (unused after fusion)
  float* Am     = (float*)alloc((size_t)4096 * 256 * 4);
  u16* Ad  = (u16*)alloc((size_t)1048576 * 2);
  u16* h1  = (u16*)alloc((size_t)4096 * 512 * 2);
  float* ffb = (float*)alloc((size_t)4096 * 256 * 4);
  (void)attn_o;

  detect_kernel<<<1, 256, 0, stream>>>((const u16*)d_in[0], flag);

  ConvJobs J{};
  auto setj = [&](int i, const void* s, void* d, void* d2, int n, int m){
    J.src[i] = s; J.dst[i] = d; J.dst2[i] = d2; J.n[i] = n; J.mode[i] = m;
  };
  setj(0,  d_in[0],  Qc,  Qlo, 1048576, 1);
  setj(1,  d_in[1],  Hc,  Hlo, 1048576, 1);
  setj(2,  d_in[2],  Ac,  nullptr, 1048576, 0);
  setj(3,  d_in[3],  wqc, nullptr, 524288, 0);
  setj(4,  d_in[5],  wkc, nullptr, 524288, 0);
  setj(5,  d_in[7],  wvc, nullptr, 524288, 0);
  setj(6,  d_in[9],  woc, nullptr, 524288, 0);
  setj(7,  d_in[14], w1c, nullptr, 131072, 0);
  setj(8,  d_in[16], w2c, nullptr, 131072, 0);
  setj(9,  d_in[4],  p_bq, nullptr, 2048, 2);
  setj(10, d_in[6],  p_bk, nullptr, 2048, 2);
  setj(11, d_in[8],  p_bv, nullptr, 2048, 2);
  setj(12, d_in[10], p_bo, nullptr, 256, 2);
  setj(13, d_in[15], p_b1, nullptr, 512, 2);
  setj(14, d_in[17], p_b2, nullptr, 256, 2);
  setj(15, d_in[12], p_g,  nullptr, 256, 2);
  setj(16, d_in[13], p_b,  nullptr, 256, 2);
  setj(17, d_in[11], p_scale, nullptr, 1, 2);
  convert_all<<<dim3(64, 18), 256, 0, stream>>>(J, flag);

  // QKV projections: ONE launch, z selects job (V stores transposed-per-head)
  gemm_qkv<<<dim3(32, 16, 3), 256, 0, stream>>>(Qc, Hc, Ac, wqc, wkc, wvc,
                                                p_bq, p_bk, p_bv, qbuf, kbuf, vtb);
  transpose_k<<<dim3(32, 4, 2), 256, 0, stream>>>(Ac, At);

  // MHA flash (R14 verified)
  flash_mha<<<dim3(256), 512, 0, stream>>>(qbuf, kbuf, vtb, ctx);

  // branch2 flash, split-K into 8 chunks (partials into dead qbuf/kbuf + vtb)
  float* Opart = (float*)qbuf;      // 32 MB spans qbuf+kbuf (contiguous)
  float* mlbuf = (float*)vtb;
  flash_b2<<<dim3(32, 2, 8), 256, 0, stream>>>(Qc, Qlo, Hc, Hlo, At,
                                               Opart, mlbuf, p_scale, flag);

  // output projection, then fused merge+LN, then FFN + final LN
  gemm_bt64<1, false><<<dim3(64, 4), 256, 0, stream>>>(ctx, woc, p_bo, Am, 4096, 256, 2048);
  ln_merge<<<1024, 256, 0, stream>>>(Opart, mlbuf, Am, p_g, p_b, Ad);
  gemm_bt64<0, true ><<<dim3(64, 8), 256, 0, stream>>>(Ad, w1c, p_b1, h1, 4096, 512, 256);
  gemm_bt64<1, false><<<dim3(64, 4), 256, 0, stream>>>(h1, w2c, p_b2, ffb, 4096, 256, 512);
  ln_k<0, 1><<<1024, 256, 0, stream>>>(ffb, Ad, p_g, p_b, d_out, flag);
}

// Round 16
// 264.802 us; speedup vs baseline: 1.0861x; 1.0210x over previous
//
#include <hip/hip_runtime.h>
#include <cstdint>
#include <cstddef>

// ---------------------------------------------------------------------------
// DeductionNetworkSingleLayer.  R16 = R15 + launch eliminations:
//  (1) detect_kernel folded into convert_all (local per-block detection;
//      block (0,0) publishes *flag for downstream kernels)
//  (2) transpose_k folded into gemm_qkv as z=3 (LDS tile overlays lx)
// All verified compute paths byte-identical to R15 (270.4us).
// ---------------------------------------------------------------------------

typedef unsigned short u16;
typedef __attribute__((ext_vector_type(8))) short bf16x8;
typedef __attribute__((ext_vector_type(4))) short s16x4;
typedef __attribute__((ext_vector_type(4))) float f32x4;

__device__ __forceinline__ float b2f(u16 u){
  union { unsigned int i; float f; } v; v.i = ((unsigned int)u) << 16; return v.f;
}
__device__ __forceinline__ u16 f2b(float f){
  union { float f; unsigned int i; } v; v.f = f;
  unsigned int u = v.i;
  unsigned int r = (u + 0x7FFFu + ((u >> 16) & 1u)) >> 16;
  return (u16)r;
}
__device__ __forceinline__ f32x4 mfma16(bf16x8 a, bf16x8 b, f32x4 c){
  return __builtin_amdgcn_mfma_f32_16x16x32_bf16(a, b, c, 0, 0, 0);
}
__device__ __forceinline__ void gload_lds16(const void* g, void* l){
  __builtin_amdgcn_global_load_lds(
      (const __attribute__((address_space(1))) unsigned int*)g,
      (__attribute__((address_space(3))) unsigned int*)l, 16, 0, 0);
}

// ---------------------------------------------------------------------------
struct ConvJobs {
  const void* src[18];
  void*       dst[18];
  void*       dst2[18];
  int         n[18];
  int         mode[18];   // 0 = bf16 hi, 1 = bf16 hi+lo, 2 = f32 out
};

// convert_all with inline dtype detection: every block scans Q[0:2048] read
// as u16 (fp32 data has ~45% wild exponents) -> deterministic local isf.
// Block (0,0) also publishes *flag for flash_b2 / final ln_k.
__global__ void convert_all(ConvJobs J, const u16* __restrict__ qsrc,
                            int* __restrict__ flag){
  __shared__ int cnt;
  if (threadIdx.x == 0) cnt = 0;
  __syncthreads();
  int c = 0;
  for (int i = threadIdx.x; i < 2048; i += 256){
    u16 u = qsrc[i];
    int e = (u >> 7) & 0xFF;
    if (e >= 140) c++;
  }
  atomicAdd(&cnt, c);
  __syncthreads();
  const int isf = (cnt > 64) ? 1 : 0;
  if (blockIdx.x == 0 && blockIdx.y == 0 && threadIdx.x == 0) *flag = isf;

  const int j = blockIdx.y;
  const int n = J.n[j];
  const int mode = J.mode[j];
  for (int i = blockIdx.x * blockDim.x + threadIdx.x; i < n; i += gridDim.x * blockDim.x){
    if (mode == 2){
      float f = isf ? ((const float*)J.src[j])[i] : b2f(((const u16*)J.src[j])[i]);
      ((float*)J.dst[j])[i] = f;
    } else {
      u16 hi, lo = 0;
      if (isf){
        float f = ((const float*)J.src[j])[i];
        hi = f2b(f);
        if (mode == 1) lo = f2b(f - b2f(hi));
      } else {
        hi = ((const u16*)J.src[j])[i];
      }
      ((u16*)J.dst[j])[i] = hi;
      if (mode == 1) ((u16*)J.dst2[j])[i] = lo;
    }
  }
}

// ---------------------------------------------------------------------------
// gemm_qkv: all three QKV projections + the A-transpose in ONE launch.
// grid (32,16,4); z<3 selects {X,W,bias,out,store-mode}; z==3 runs the
// 64x64 bf16 transpose At[b][d][sk] = Ac[b][sk][d] (jobs 0..255).
// ---------------------------------------------------------------------------
__global__ __launch_bounds__(256) void gemm_qkv(
    const u16* __restrict__ Qc, const u16* __restrict__ Hc, const u16* __restrict__ Ac,
    const u16* __restrict__ wq, const u16* __restrict__ wk, const u16* __restrict__ wv,
    const float* __restrict__ bq, const float* __restrict__ bk, const float* __restrict__ bv,
    u16* __restrict__ qo, u16* __restrict__ ko, u16* __restrict__ vo,
    u16* __restrict__ At)
{
  __shared__ __align__(16) u16 lx[128 * 64];
  __shared__ __align__(16) u16 lw[128 * 64];
  const int z = blockIdx.z;
  const int tid = threadIdx.x;

  if (z == 3){
    // ---- transpose path: job = bx + 32*by, 256 jobs ----
    const int job = blockIdx.x + (blockIdx.y << 5);
    if (job >= 256) return;
    u16 (*t)[72] = (u16(*)[72])lx;          // 64x72 u16 = 9KB, overlays lx
    const int b   = job >> 7;               // 0..1
    const int d0  = ((job >> 5) & 3) * 64;
    const int sk0 = (job & 31) * 64;
    union U8 { bf16x8 v; u16 e[8]; };
#pragma unroll
    for (int half = 0; half < 2; ++half){
      int c = half * 256 + tid;
      int r = c >> 3, c8 = (c & 7) * 8;
      U8 u; u.v = *(const bf16x8*)(Ac + ((size_t)b * 2048 + sk0 + r) * 256 + d0 + c8);
#pragma unroll
      for (int i = 0; i < 8; i++) t[r][c8 + i] = u.e[i];
    }
    __syncthreads();
#pragma unroll
    for (int half = 0; half < 2; ++half){
      int c = half * 256 + tid;
      int dr = c >> 3, s8 = (c & 7) * 8;
      U8 u;
#pragma unroll
      for (int i = 0; i < 8; i++) u.e[i] = t[s8 + i][dr];
      *(bf16x8*)(At + ((size_t)b * 256 + d0 + dr) * 2048 + sk0 + s8) = u.v;
    }
    return;
  }

  // ---- GEMM path (verified 128x128 swizzled structure) ----
  const u16* X = (z == 0) ? Qc : (z == 1) ? Hc : Ac;
  const u16* W = (z == 0) ? wq : (z == 1) ? wk : wv;
  const float* bias = (z == 0) ? bq : (z == 1) ? bk : bv;
  u16* outp = (z == 0) ? qo : (z == 1) ? ko : vo;
  const bool vstore = (z == 2);
  const int K = 256, N = 2048;

  const int l = tid & 63, w = tid >> 6;
  const int lg = l >> 4, lr = l & 15;
  const int wr = w >> 1, wc = w & 1;
  const int m0 = blockIdx.x * 128;
  const int n0 = blockIdx.y * 128;

  f32x4 acc[4][4];
#pragma unroll
  for (int mi = 0; mi < 4; mi++)
#pragma unroll
    for (int ni = 0; ni < 4; ni++) acc[mi][ni] = (f32x4){0.f, 0.f, 0.f, 0.f};

  for (int kt = 0; kt < 4; ++kt){
    __syncthreads();
#pragma unroll
    for (int it = 0; it < 4; ++it){
      int c = it * 256 + tid;
      int row = c >> 3, j = c & 7;
      int sj = (j ^ (row & 7)) * 8;
      const u16* gx = X + (size_t)(m0 + row) * K + kt * 64 + sj;
      gload_lds16(gx, (char*)lx + c * 16);
      const u16* gw = W + (size_t)(n0 + row) * K + kt * 64 + sj;
      gload_lds16(gw, (char*)lw + c * 16);
    }
    __syncthreads();
#pragma unroll
    for (int ks = 0; ks < 2; ++ks){
      bf16x8 af[4], bfv[4];
      const int swz = ((ks * 4 + lg) ^ (lr & 7)) * 8;
#pragma unroll
      for (int mi = 0; mi < 4; mi++)
        af[mi] = *(const bf16x8*)(lx + (wr * 64 + mi * 16 + lr) * 64 + swz);
#pragma unroll
      for (int ni = 0; ni < 4; ni++)
        bfv[ni] = *(const bf16x8*)(lw + (wc * 64 + ni * 16 + lr) * 64 + swz);
#pragma unroll
      for (int mi = 0; mi < 4; mi++)
#pragma unroll
        for (int ni = 0; ni < 4; ni++)
          acc[mi][ni] = mfma16(af[mi], bfv[ni], acc[mi][ni]);
    }
  }

#pragma unroll
  for (int mi = 0; mi < 4; mi++)
#pragma unroll
    for (int ni = 0; ni < 4; ni++){
      const int gr0 = m0 + wr * 64 + mi * 16 + lg * 4;
      const int gc  = n0 + wc * 64 + ni * 16 + lr;
      const float bv2 = bias[gc];
      if (vstore){
        const int b = gr0 >> 11, sk0 = gr0 & 2047;
        const int h = gc >> 8,  d   = gc & 255;
        s16x4 pk;
#pragma unroll
        for (int r = 0; r < 4; r++) pk[r] = (short)f2b(acc[mi][ni][r] + bv2);
        *(s16x4*)(outp + ((size_t)((b << 3) + h) * 256 + d) * 2048 + sk0) = pk;
      } else {
#pragma unroll
        for (int r = 0; r < 4; r++)
          outp[(size_t)(gr0 + r) * N + gc] = f2b(acc[mi][ni][r] + bv2);
      }
    }
}

// ---------------------------------------------------------------------------
// GEMM 64x64 tile variant: fills the grid for small-N GEMMs (wo, w1, w2).
// ---------------------------------------------------------------------------
template<int STORE, bool RELU>
__global__ __launch_bounds__(256) void gemm_bt64(
    const u16* __restrict__ X, const u16* __restrict__ W,
    const float* __restrict__ bias, void* __restrict__ outp,
    int M, int N, int K)
{
  __shared__ __align__(16) u16 lx[64 * 64];
  __shared__ __align__(16) u16 lw[64 * 64];
  const int tid = threadIdx.x;
  const int l = tid & 63, w = tid >> 6;
  const int lg = l >> 4, lr = l & 15;
  const int wr = w >> 1, wc = w & 1;
  const int m0 = blockIdx.x * 64;
  const int n0 = blockIdx.y * 64;

  f32x4 acc[2][2];
#pragma unroll
  for (int mi = 0; mi < 2; mi++)
#pragma unroll
    for (int ni = 0; ni < 2; ni++) acc[mi][ni] = (f32x4){0.f, 0.f, 0.f, 0.f};

  const int nkt = K >> 6;
  for (int kt = 0; kt < nkt; ++kt){
    __syncthreads();
#pragma unroll
    for (int it = 0; it < 2; ++it){
      int c = it * 256 + tid;
      int row = c >> 3, j = c & 7;
      int sj = (j ^ (row & 7)) * 8;
      const u16* gx = X + (size_t)(m0 + row) * K + kt * 64 + sj;
      gload_lds16(gx, (char*)lx + c * 16);
      const u16* gw = W + (size_t)(n0 + row) * K + kt * 64 + sj;
      gload_lds16(gw, (char*)lw + c * 16);
    }
    __syncthreads();
#pragma unroll
    for (int ks = 0; ks < 2; ++ks){
      bf16x8 af[2], bfv[2];
      const int swz = ((ks * 4 + lg) ^ (lr & 7)) * 8;
#pragma unroll
      for (int mi = 0; mi < 2; mi++)
        af[mi] = *(const bf16x8*)(lx + (wr * 32 + mi * 16 + lr) * 64 + swz);
#pragma unroll
      for (int ni = 0; ni < 2; ni++)
        bfv[ni] = *(const bf16x8*)(lw + (wc * 32 + ni * 16 + lr) * 64 + swz);
#pragma unroll
      for (int mi = 0; mi < 2; mi++)
#pragma unroll
        for (int ni = 0; ni < 2; ni++)
          acc[mi][ni] = mfma16(af[mi], bfv[ni], acc[mi][ni]);
    }
  }

#pragma unroll
  for (int mi = 0; mi < 2; mi++)
#pragma unroll
    for (int ni = 0; ni < 2; ni++){
      const int gr0 = m0 + wr * 32 + mi * 16 + lg * 4;
      const int gc  = n0 + wc * 32 + ni * 16 + lr;
      const float bv = bias ? bias[gc] : 0.f;
#pragma unroll
      for (int r = 0; r < 4; r++){
        float v = acc[mi][ni][r] + bv;
        if (RELU) v = fmaxf(v, 0.f);
        size_t idx = (size_t)(gr0 + r) * N + gc;
        if (STORE == 0) ((u16*)outp)[idx] = f2b(v);
        else            ((float*)outp)[idx] = v;
      }
    }
}

// ---------------------------------------------------------------------------
// flash_mha: R14 verified (116us).  512 threads (8 waves), 16 q-rows/wave,
// double-buffered K/V (144KB LDS), 2-tile-deep prefetch, counted vmcnt(8) +
// raw s_barrier.  1D grid 256, XCD-aware decode (xcd=bid&7 owns 2 heads).
// ---------------------------------------------------------------------------
__global__ __launch_bounds__(512, 2) void flash_mha(
    const u16* __restrict__ Qp, const u16* __restrict__ Kp,
    const u16* __restrict__ Vt, u16* __restrict__ outp)
{
  __shared__ __align__(16) u16 bufK[2][64 * 256];   // 64KB
  __shared__ __align__(16) u16 bufV[2][256 * 64];   // 64KB
  __shared__ __align__(16) u16 ldsP[8][16 * 64];    // 16KB (swz)
  const int tid = threadIdx.x, l = tid & 63, w = tid >> 6;
  const int lg = l >> 4, lr = l & 15;
  const int lr7 = lr & 7;
  const int bid = blockIdx.x;
  const int xcd = bid & 7;
  const int slot = bid >> 3;
  const int by = xcd * 2 + (slot >> 4);
  const int qt = slot & 15;
  const size_t qkbase = ((size_t)(by >> 3) * 2048) * 2048 + (size_t)(by & 7) * 256;
  const size_t vbase  = (size_t)by * (256 * 2048);
  const int q0 = qt * 128 + w * 16;

  bf16x8 qf[8];
#pragma unroll
  for (int ks = 0; ks < 8; ks++)
    qf[ks] = *(const bf16x8*)(Qp + qkbase +
        (size_t)(q0 + lr) * 2048 + ks * 32 + lg * 8);

  float mrun[4], lpart[4];
#pragma unroll
  for (int r = 0; r < 4; r++){ mrun[r] = -3e38f; lpart[r] = 0.f; }
  f32x4 accO[16];
#pragma unroll
  for (int db = 0; db < 16; db++) accO[db] = (f32x4){0.f, 0.f, 0.f, 0.f};

  auto stageK = [&](int kv0, u16* dst){
#pragma unroll
    for (int it = 0; it < 4; ++it){
      int c = it * 512 + tid;
      int row = c >> 5, j = c & 31;
      const u16* g = Kp + qkbase + (size_t)(kv0 + row) * 2048 + (j ^ (row & 7)) * 8;
      gload_lds16(g, (char*)dst + c * 16);
    }
  };
  auto stageV = [&](int kv0, u16* dst){
#pragma unroll
    for (int it = 0; it < 4; ++it){
      int c = it * 512 + tid;
      int row = c >> 3, j = c & 7;
      const u16* g = Vt + vbase + (size_t)row * 2048 + kv0 + (j ^ (row & 7)) * 8;
      gload_lds16(g, (char*)dst + c * 16);
    }
  };

  stageK(0,  bufK[0]); stageV(0,  bufV[0]);
  stageK(64, bufK[1]); stageV(64, bufV[1]);

  for (int t = 0; t < 32; ++t){
    const int kv0 = t * 64;
    const int cur = t & 1;
    if (t < 31) asm volatile("s_waitcnt vmcnt(8)" ::: "memory");
    else        asm volatile("s_waitcnt vmcnt(0)" ::: "memory");
    asm volatile("s_barrier" ::: "memory");

    f32x4 s[4];
#pragma unroll
    for (int kb = 0; kb < 4; kb++) s[kb] = (f32x4){0.f, 0.f, 0.f, 0.f};

    __builtin_amdgcn_s_setprio(1);
#pragma unroll
    for (int ks = 0; ks < 8; ks++){
      bf16x8 bfr[4];
      const int swz = (((ks * 4 + lg) ^ lr7)) * 8;
#pragma unroll
      for (int kb = 0; kb < 4; kb++)
        bfr[kb] = *(const bf16x8*)(bufK[cur] + (kb * 16 + lr) * 256 + swz);
#pragma unroll
      for (int kb = 0; kb < 4; kb++)
        s[kb] = mfma16(qf[ks], bfr[kb], s[kb]);
    }
    __builtin_amdgcn_s_setprio(0);

    float pm[4];
#pragma unroll
    for (int kb = 0; kb < 4; kb++)
#pragma unroll
      for (int r = 0; r < 4; r++) s[kb][r] *= 0.0625f;
#pragma unroll
    for (int r = 0; r < 4; r++)
      pm[r] = fmaxf(fmaxf(s[0][r], s[1][r]), fmaxf(s[2][r], s[3][r]));
#pragma unroll
    for (int m = 1; m < 16; m <<= 1)
#pragma unroll
      for (int r = 0; r < 4; r++) pm[r] = fmaxf(pm[r], __shfl_xor(pm[r], m));

    float gmax = fmaxf(fmaxf(pm[0] - mrun[0], pm[1] - mrun[1]),
                       fmaxf(pm[2] - mrun[2], pm[3] - mrun[3]));
    if (__any(gmax > 8.0f)){
#pragma unroll
      for (int r = 0; r < 4; r++){
        float mn = fmaxf(mrun[r], pm[r]);
        float corr = __expf(mrun[r] - mn);
        mrun[r] = mn;
        lpart[r] *= corr;
#pragma unroll
        for (int db = 0; db < 16; db++) accO[db][r] *= corr;
      }
    }
#pragma unroll
    for (int kb = 0; kb < 4; kb++)
#pragma unroll
      for (int r = 0; r < 4; r++){
        float p = __expf(s[kb][r] - mrun[r]);
        lpart[r] += p;
        const int row = lg * 4 + r;
        ldsP[w][(row << 6) + (((kb * 2 + (lr >> 3)) ^ (row & 7)) << 3) + (lr & 7)] = f2b(p);
      }

    __builtin_amdgcn_s_setprio(1);
#pragma unroll
    for (int ks2 = 0; ks2 < 2; ++ks2){
      bf16x8 pa = *(const bf16x8*)(ldsP[w] + (lr << 6) + (((ks2 * 4 + lg) ^ lr7) << 3));
      const int swz = (((ks2 * 4 + lg) ^ lr7)) * 8;
#pragma unroll
      for (int db = 0; db < 16; ++db){
        bf16x8 vb = *(const bf16x8*)(bufV[cur] + (db * 16 + lr) * 64 + swz);
        accO[db] = mfma16(pa, vb, accO[db]);
      }
    }
    __builtin_amdgcn_s_setprio(0);

    asm volatile("s_barrier" ::: "memory");
    if (t + 2 < 32){
      stageK(kv0 + 128, bufK[cur]);
      stageV(kv0 + 128, bufV[cur]);
    }
  }

  float lrun[4];
#pragma unroll
  for (int r = 0; r < 4; r++) lrun[r] = lpart[r];
#pragma unroll
  for (int m = 1; m < 16; m <<= 1)
#pragma unroll
    for (int r = 0; r < 4; r++) lrun[r] += __shfl_xor(lrun[r], m);
  float inv[4];
#pragma unroll
  for (int r = 0; r < 4; r++) inv[r] = 1.f / lrun[r];
#pragma unroll
  for (int db = 0; db < 16; db++)
#pragma unroll
    for (int r = 0; r < 4; r++){
      float v = accO[db][r] * inv[r];
      int q = q0 + lg * 4 + r;
      int d = db * 16 + lr;
      outp[((size_t)(by >> 3) * 2048 + q) * 2048 + (size_t)(by & 7) * 256 + d] = f2b(v);
    }
}

// ---------------------------------------------------------------------------
// flash_b2: split-K branch2, grid (32,2,8).
// ---------------------------------------------------------------------------
__global__ __launch_bounds__(256) void flash_b2(
    const u16* __restrict__ Qh, const u16* __restrict__ Ql,
    const u16* __restrict__ Kh, const u16* __restrict__ Kl,
    const u16* __restrict__ Vt,
    float* __restrict__ Opart, float* __restrict__ mlp,
    const float* __restrict__ p_scale, const int* __restrict__ flagp)
{
  __shared__ __align__(16) u16 bufK[64 * 256];
  __shared__ __align__(16) u16 bufV[256 * 64];
  __shared__ __align__(16) u16 ldsP[4][16 * 72];
  const int tid = threadIdx.x, l = tid & 63, w = tid >> 6;
  const int lg = l >> 4, lr = l & 15;
  const int lr7 = lr & 7;
  const int by = blockIdx.y, qt = blockIdx.x, kc = blockIdx.z;
  const size_t qkbase = (size_t)by * (2048 * 256);
  const size_t vbase  = (size_t)by * (256 * 2048);
  const float scale = *p_scale;
  const int split = *flagp;
  const int kvbase = kc * 256;
  const int q0 = qt * 64 + w * 16;

  bf16x8 qf[8], qfl[8];
#pragma unroll
  for (int ks = 0; ks < 8; ks++)
    qf[ks] = *(const bf16x8*)(Qh + qkbase + (size_t)(q0 + lr) * 256 + ks * 32 + lg * 8);
  if (split){
#pragma unroll
    for (int ks = 0; ks < 8; ks++)
      qfl[ks] = *(const bf16x8*)(Ql + qkbase + (size_t)(q0 + lr) * 256 + ks * 32 + lg * 8);
  } else {
#pragma unroll
    for (int ks = 0; ks < 8; ks++) qfl[ks] = qf[ks];
  }

  float mrun[4], lpart[4];
#pragma unroll
  for (int r = 0; r < 4; r++){ mrun[r] = -3e38f; lpart[r] = 0.f; }
  f32x4 accO[16];
#pragma unroll
  for (int db = 0; db < 16; db++) accO[db] = (f32x4){0.f, 0.f, 0.f, 0.f};

  auto stageK = [&](const u16* __restrict__ src, int kv0){
#pragma unroll
    for (int it = 0; it < 8; ++it){
      int c = it * 256 + tid;
      int row = c >> 5, j = c & 31;
      const u16* g = src + qkbase + (size_t)(kv0 + row) * 256 + (j ^ (row & 7)) * 8;
      gload_lds16(g, (char*)bufK + c * 16);
    }
  };
  auto stageV = [&](int kv0){
#pragma unroll
    for (int it = 0; it < 8; ++it){
      int c = it * 256 + tid;
      int row = c >> 3, j = c & 7;
      const u16* g = Vt + vbase + (size_t)row * 2048 + kv0 + (j ^ (row & 7)) * 8;
      gload_lds16(g, (char*)bufV + c * 16);
    }
  };

  for (int t = 0; t < 4; ++t){
    const int kv0 = kvbase + t * 64;
    __syncthreads();
    stageK(Kh, kv0);
    stageV(kv0);
    __syncthreads();

    f32x4 s[4];
#pragma unroll
    for (int kb = 0; kb < 4; kb++) s[kb] = (f32x4){0.f, 0.f, 0.f, 0.f};
#pragma unroll
    for (int ks = 0; ks < 8; ks++){
      bf16x8 bfr[4];
      const int swz = (((ks * 4 + lg) ^ lr7)) * 8;
#pragma unroll
      for (int kb = 0; kb < 4; kb++)
        bfr[kb] = *(const bf16x8*)(bufK + (kb * 16 + lr) * 256 + swz);
#pragma unroll
      for (int kb = 0; kb < 4; kb++) s[kb] = mfma16(qf[ks], bfr[kb], s[kb]);
      if (split){
#pragma unroll
        for (int kb = 0; kb < 4; kb++) s[kb] = mfma16(qfl[ks], bfr[kb], s[kb]);
      }
    }
    if (split){
      __syncthreads();
      stageK(Kl, kv0);
      __syncthreads();
#pragma unroll
      for (int ks = 0; ks < 8; ks++){
        bf16x8 bfr[4];
        const int swz = (((ks * 4 + lg) ^ lr7)) * 8;
#pragma unroll
        for (int kb = 0; kb < 4; kb++)
          bfr[kb] = *(const bf16x8*)(bufK + (kb * 16 + lr) * 256 + swz);
#pragma unroll
        for (int kb = 0; kb < 4; kb++) s[kb] = mfma16(qf[ks], bfr[kb], s[kb]);
      }
    }

#pragma unroll
    for (int kb = 0; kb < 4; kb++)
#pragma unroll
      for (int r = 0; r < 4; r++) s[kb][r] *= scale;

    float pm[4];
#pragma unroll
    for (int r = 0; r < 4; r++)
      pm[r] = fmaxf(fmaxf(s[0][r], s[1][r]), fmaxf(s[2][r], s[3][r]));
#pragma unroll
    for (int m = 1; m < 16; m <<= 1)
#pragma unroll
      for (int r = 0; r < 4; r++) pm[r] = fmaxf(pm[r], __shfl_xor(pm[r], m));

    float g = fmaxf(fmaxf(pm[0] - mrun[0], pm[1] - mrun[1]),
                    fmaxf(pm[2] - mrun[2], pm[3] - mrun[3]));
    if (__any(g > 8.0f)){
#pragma unroll
      for (int r = 0; r < 4; r++){
        float mn = fmaxf(mrun[r], pm[r]);
        float corr = __expf(mrun[r] - mn);
        mrun[r] = mn;
        lpart[r] *= corr;
#pragma unroll
        for (int db = 0; db < 16; db++) accO[db][r] *= corr;
      }
    }
#pragma unroll
    for (int kb = 0; kb < 4; kb++)
#pragma unroll
      for (int r = 0; r < 4; r++){
        float p = __expf(s[kb][r] - mrun[r]);
        lpart[r] += p;
        ldsP[w][(lg * 4 + r) * 72 + kb * 16 + lr] = f2b(p);
      }

#pragma unroll
    for (int ks2 = 0; ks2 < 2; ++ks2){
      bf16x8 pa = *(const bf16x8*)(ldsP[w] + lr * 72 + ks2 * 32 + lg * 8);
      const int swz = (((ks2 * 4 + lg) ^ lr7)) * 8;
#pragma unroll
      for (int db = 0; db < 16; ++db){
        bf16x8 vb = *(const bf16x8*)(bufV + (db * 16 + lr) * 64 + swz);
        accO[db] = mfma16(pa, vb, accO[db]);
      }
    }
  }

  float lrun[4];
#pragma unroll
  for (int r = 0; r < 4; r++) lrun[r] = lpart[r];
#pragma unroll
  for (int m = 1; m < 16; m <<= 1)
#pragma unroll
    for (int r = 0; r < 4; r++) lrun[r] += __shfl_xor(lrun[r], m);

#pragma unroll
  for (int db = 0; db < 16; db++)
#pragma unroll
    for (int r = 0; r < 4; r++){
      int q = q0 + lg * 4 + r;
      int d = db * 16 + lr;
      Opart[((size_t)((kc * 2 + by) * 2048 + q)) * 256 + d] = accO[db][r];
    }
  if (lr == 0){
#pragma unroll
    for (int r = 0; r < 4; r++){
      int idx = (kc * 2 + by) * 2048 + q0 + lg * 4 + r;
      mlp[idx] = mrun[r];
      mlp[32768 + idx] = lrun[r];
    }
  }
}

// ---------------------------------------------------------------------------
// ln_merge: fused (merge 8 split-K partials) + (LN(Am + merged) -> Ad bf16).
// ---------------------------------------------------------------------------
__global__ __launch_bounds__(256) void ln_merge(
    const float* __restrict__ Opart, const float* __restrict__ ml,
    const float* __restrict__ Am,
    const float* __restrict__ g, const float* __restrict__ bb,
    u16* __restrict__ outp)
{
  const int w = threadIdx.x >> 6, l = threadIdx.x & 63;
  const int row = blockIdx.x * 4 + w;          // b*2048 + q
  const int b = row >> 11, q = row & 2047;
  float m[8], li[8], M = -3e38f;
#pragma unroll
  for (int kc = 0; kc < 8; kc++){
    int idx = (kc * 2 + b) * 2048 + q;
    m[kc] = ml[idx];
    li[kc] = ml[32768 + idx];
    M = fmaxf(M, m[kc]);
  }
  float L = 0.f, wgt[8];
#pragma unroll
  for (int kc = 0; kc < 8; kc++){ wgt[kc] = __expf(m[kc] - M); L += li[kc] * wgt[kc]; }
  const float invL = 1.f / L;
  f32x4 o = (f32x4){0.f, 0.f, 0.f, 0.f};
#pragma unroll
  for (int kc = 0; kc < 8; kc++){
    f32x4 v = *(const f32x4*)(Opart + ((size_t)((kc * 2 + b) * 2048 + q)) * 256 + l * 4);
#pragma unroll
    for (int i = 0; i < 4; i++) o[i] += v[i] * wgt[kc];
  }
  const size_t off = (size_t)row * 256 + l * 4;
  f32x4 xv = *(const f32x4*)(Am + off);
  float v[4];
#pragma unroll
  for (int i = 0; i < 4; i++) v[i] = xv[i] + o[i] * invL;

  float s = 0.f, sq = 0.f;
#pragma unroll
  for (int i = 0; i < 4; i++){ s += v[i]; sq += v[i] * v[i]; }
  for (int mm = 1; mm < 64; mm <<= 1){ s += __shfl_xor(s, mm); sq += __shfl_xor(sq, mm); }
  const float mean = s * (1.f / 256.f);
  const float var = sq * (1.f / 256.f) - mean * mean;
  const float rstd = rsqrtf(var + 1e-5f);
  s16x4 ov;
#pragma unroll
  for (int i = 0; i < 4; i++)
    ov[i] = (short)f2b((v[i] - mean) * rstd * g[l * 4 + i] + bb[l * 4 + i]);
  *(s16x4*)(outp + off) = ov;
}

// ---------------------------------------------------------------------------
// LayerNorm over 256: out = LN(x + res).  (final LN only)
// ---------------------------------------------------------------------------
template<int RESF32, int OUTFLAG>
__global__ __launch_bounds__(256) void ln_k(
    const float* __restrict__ x, const void* __restrict__ res,
    const float* __restrict__ g, const float* __restrict__ bb,
    void* __restrict__ outp, const int* __restrict__ flagp)
{
  const int w = threadIdx.x >> 6, l = threadIdx.x & 63;
  const int row = blockIdx.x * 4 + w;
  const size_t off = (size_t)row * 256 + l * 4;
  f32x4 xv = *(const f32x4*)(x + off);
  float v[4];
  if (RESF32){
    f32x4 rv = *(const f32x4*)((const float*)res + off);
#pragma unroll
    for (int i = 0; i < 4; i++) v[i] = xv[i] + rv[i];
  } else {
    const u16* rp = (const u16*)res + off;
#pragma unroll
    for (int i = 0; i < 4; i++) v[i] = xv[i] + b2f(rp[i]);
  }
  float s = 0.f, sq = 0.f;
#pragma unroll
  for (int i = 0; i < 4; i++){ s += v[i]; sq += v[i] * v[i]; }
  for (int m = 1; m < 64; m <<= 1){ s += __shfl_xor(s, m); sq += __shfl_xor(sq, m); }
  const float mean = s * (1.f / 256.f);
  const float var = sq * (1.f / 256.f) - mean * mean;
  const float rstd = rsqrtf(var + 1e-5f);
  float y[4];
#pragma unroll
  for (int i = 0; i < 4; i++) y[i] = (v[i] - mean) * rstd * g[l * 4 + i] + bb[l * 4 + i];
  const bool f32out = OUTFLAG && (*flagp);
  if (f32out){
    f32x4 o;
#pragma unroll
    for (int i = 0; i < 4; i++) o[i] = y[i];
    *(f32x4*)((float*)outp + off) = o;
  } else {
    s16x4 o;
#pragma unroll
    for (int i = 0; i < 4; i++) o[i] = (short)f2b(y[i]);
    *(s16x4*)((u16*)outp + off) = o;
  }
}

// ---------------------------------------------------------------------------
extern "C" void kernel_launch(void* const* d_in, const int* in_sizes, int n_in,
                              void* d_out, int out_size, void* d_ws, size_t ws_size,
                              hipStream_t stream)
{
  (void)in_sizes; (void)n_in; (void)out_size; (void)ws_size;
  char* ws = (char*)d_ws;
  size_t off = 0;
  auto alloc = [&](size_t bytes) -> char* {
    char* p = ws + off;
    off += (bytes + 255) & ~(size_t)255;
    return p;
  };
  int*   flag    = (int*)  alloc(4);
  float* p_scale = (float*)alloc(4);
  float* p_bq    = (float*)alloc(2048 * 4);
  float* p_bk    = (float*)alloc(2048 * 4);
  float* p_bv    = (float*)alloc(2048 * 4);
  float* p_bo    = (float*)alloc(256 * 4);
  float* p_b1    = (float*)alloc(512 * 4);
  float* p_b2    = (float*)alloc(256 * 4);
  float* p_g     = (float*)alloc(256 * 4);
  float* p_b     = (float*)alloc(256 * 4);
  u16* Qc  = (u16*)alloc((size_t)1048576 * 2);
  u16* Qlo = (u16*)alloc((size_t)1048576 * 2);
  u16* Hc  = (u16*)alloc((size_t)1048576 * 2);
  u16* Hlo = (u16*)alloc((size_t)1048576 * 2);
  u16* Ac  = (u16*)alloc((size_t)1048576 * 2);
  u16* wqc = (u16*)alloc((size_t)524288 * 2);
  u16* wkc = (u16*)alloc((size_t)524288 * 2);
  u16* wvc = (u16*)alloc((size_t)524288 * 2);
  u16* woc = (u16*)alloc((size_t)524288 * 2);
  u16* w1c = (u16*)alloc((size_t)131072 * 2);
  u16* w2c = (u16*)alloc((size_t)131072 * 2);
  u16* qbuf = (u16*)alloc((size_t)4096 * 2048 * 2);   // reused: Opart (with kbuf)
  u16* kbuf = (u16*)alloc((size_t)4096 * 2048 * 2);
  u16* vtb  = (u16*)alloc((size_t)4096 * 2048 * 2);   // reused: ml buffer
  u16* ctx  = (u16*)alloc((size_t)4096 * 2048 * 2);
  u16* At   = (u16*)alloc((size_t)1048576 * 2);
  float* Am     = (float*)alloc((size_t)4096 * 256 * 4);
  u16* Ad  = (u16*)alloc((size_t)1048576 * 2);
  u16* h1  = (u16*)alloc((size_t)4096 * 512 * 2);
  float* ffb = (float*)alloc((size_t)4096 * 256 * 4);

  ConvJobs J{};
  auto setj = [&](int i, const void* s, void* d, void* d2, int n, int m){
    J.src[i] = s; J.dst[i] = d; J.dst2[i] = d2; J.n[i] = n; J.mode[i] = m;
  };
  setj(0,  d_in[0],  Qc,  Qlo, 1048576, 1);
  setj(1,  d_in[1],  Hc,  Hlo, 1048576, 1);
  setj(2,  d_in[2],  Ac,  nullptr, 1048576, 0);
  setj(3,  d_in[3],  wqc, nullptr, 524288, 0);
  setj(4,  d_in[5],  wkc, nullptr, 524288, 0);
  setj(5,  d_in[7],  wvc, nullptr, 524288, 0);
  setj(6,  d_in[9],  woc, nullptr, 524288, 0);
  setj(7,  d_in[14], w1c, nullptr, 131072, 0);
  setj(8,  d_in[16], w2c, nullptr, 131072, 0);
  setj(9,  d_in[4],  p_bq, nullptr, 2048, 2);
  setj(10, d_in[6],  p_bk, nullptr, 2048, 2);
  setj(11, d_in[8],  p_bv, nullptr, 2048, 2);
  setj(12, d_in[10], p_bo, nullptr, 256, 2);
  setj(13, d_in[15], p_b1, nullptr, 512, 2);
  setj(14, d_in[17], p_b2, nullptr, 256, 2);
  setj(15, d_in[12], p_g,  nullptr, 256, 2);
  setj(16, d_in[13], p_b,  nullptr, 256, 2);
  setj(17, d_in[11], p_scale, nullptr, 1, 2);
  convert_all<<<dim3(64, 18), 256, 0, stream>>>(J, (const u16*)d_in[0], flag);

  // QKV projections + A-transpose: ONE launch (z=0..2 GEMM, z=3 transpose)
  gemm_qkv<<<dim3(32, 16, 4), 256, 0, stream>>>(Qc, Hc, Ac, wqc, wkc, wvc,
                                                p_bq, p_bk, p_bv, qbuf, kbuf, vtb, At);

  // MHA flash (R14 verified)
  flash_mha<<<dim3(256), 512, 0, stream>>>(qbuf, kbuf, vtb, ctx);

  // branch2 flash, split-K into 8 chunks (partials into dead qbuf/kbuf + vtb)
  float* Opart = (float*)qbuf;      // 32 MB spans qbuf+kbuf (contiguous)
  float* mlbuf = (float*)vtb;
  flash_b2<<<dim3(32, 2, 8), 256, 0, stream>>>(Qc, Qlo, Hc, Hlo, At,
                                               Opart, mlbuf, p_scale, flag);

  // output projection, then fused merge+LN, then FFN + final LN
  gemm_bt64<1, false><<<dim3(64, 4), 256, 0, stream>>>(ctx, woc, p_bo, Am, 4096, 256, 2048);
  ln_merge<<<1024, 256, 0, stream>>>(Opart, mlbuf, Am, p_g, p_b, Ad);
  gemm_bt64<0, true ><<<dim3(64, 8), 256, 0, stream>>>(Ad, w1c, p_b1, h1, 4096, 512, 256);
  gemm_bt64<1, false><<<dim3(64, 4), 256, 0, stream>>>(h1, w2c, p_b2, ffb, 4096, 256, 512);
  ln_k<0, 1><<<1024, 256, 0, stream>>>(ffb, Ad, p_g, p_b, d_out, flag);
}